// Round 1
// baseline (1341.361 us; speedup 1.0000x reference)
//
#include <hip/hip_runtime.h>
#include <math.h>

#define DIM 240
#define NE 8
#define DEPTH 8
#define BB 8
#define SS 2048
#define NTOK (BB * SS)
#define NENT (2 * NTOK)
#define TM 16
#define TWO_PI 6.28318530717958647692f

// ---------------- workspace layout (byte offsets, 256-aligned) ----------------
#define ALIGN256(x) (((x) + 255) & ~((size_t)255))
// floats
static const size_t OFF_COST   = 0;                                        // 240*240 f
static const size_t OFF_SINT   = ALIGN256(OFF_COST  + 240*240*4);          // 240*240 f
static const size_t OFF_H      = ALIGN256(OFF_SINT  + 240*240*4);          // NTOK*DIM f
static const size_t OFF_TMP    = ALIGN256(OFF_H     + (size_t)NTOK*DIM*4); // NENT*DIM f
static const size_t OFF_W01    = ALIGN256(OFF_TMP   + (size_t)NENT*DIM*4); // 2*NTOK f
static const size_t OFF_ENTW   = ALIGN256(OFF_W01   + 2*NTOK*4);           // NENT f
static const size_t OFF_OUTACC = ALIGN256(OFF_ENTW  + NENT*4);             // 8 f
// ints
static const size_t OFF_E01    = ALIGN256(OFF_OUTACC + 8*4);               // 2*NTOK i
static const size_t OFF_POS01  = ALIGN256(OFF_E01    + 2*NTOK*4);          // 2*NTOK i
static const size_t OFF_ENTTOK = ALIGN256(OFF_POS01  + 2*NTOK*4);          // NENT i
static const size_t OFF_COUNTS = ALIGN256(OFF_ENTTOK + NENT*4);            // 8 i
static const size_t OFF_OFFS   = ALIGN256(OFF_COUNTS + 8*4);               // 8 i
static const size_t OFF_CURSOR = ALIGN256(OFF_OFFS   + 8*4);               // 8 i

// ---------------- kernels ----------------

// cos/sin tables: emb[s%240, d] = sum_r roots[s%240,r]*projW[r, d%80]
__global__ void k_tables(const float* __restrict__ roots, const float* __restrict__ projW,
                         float* __restrict__ cosT, float* __restrict__ sinT) {
    int s = blockIdx.x;
    int d = threadIdx.x;
    if (d >= DIM) return;
    int j = d % 80;
    float acc = 0.f;
#pragma unroll
    for (int r = 0; r < 8; ++r) acc += roots[s*8 + r] * projW[r*80 + j];
    cosT[s*DIM + d] = cosf(acc);
    sinT[s*DIM + d] = sinf(acc);
}

// cycle block: h = (x1 + roll(x1)*sin + roll(roll(x1)*sin)*cos)/3
__global__ void k_cycle(const float* __restrict__ x, const int* __restrict__ step,
                        const float* __restrict__ cosT, const float* __restrict__ sinT,
                        float* __restrict__ h) {
    int tok = blockIdx.x;
    int d = threadIdx.x;
    if (d >= DIM) return;
    int s = tok % SS;
    int sm = s % 240;
    float pump = 0.8f * sinf((float)step[0] * 0.006f * TWO_PI);
    const float* xr = x + (size_t)tok * DIM;
    const float* cr = cosT + sm * DIM;
    const float* sr = sinT + sm * DIM;
    int dm1 = (d + DIM - 1) % DIM;
    int dm2 = (d + DIM - 2) % DIM;
    float x1d  = xr[d]   * (cr[d]   + pump);
    float x1m1 = xr[dm1] * (cr[dm1] + pump);
    float x1m2 = xr[dm2] * (cr[dm2] + pump);
    float x2d  = x1m1 * sr[d];
    float x2m1 = x1m2 * sr[dm1];
    float x3d  = x2m1 * cr[d];
    h[(size_t)tok*DIM + d] = (x1d + x2d + x3d) * (1.0f/3.0f);
}

// gate: logits = h @ gW + gb; softmax; top2; store (e0,e1,w0,w1); count per expert
__global__ void k_gate(const float* __restrict__ h, const float* __restrict__ gW,
                       const float* __restrict__ gb, int* __restrict__ e01,
                       float* __restrict__ w01, int* __restrict__ counts) {
    __shared__ float hs[32*DIM];
    __shared__ float lg[32][NE];
    __shared__ int lcnt[NE];
    int tid = threadIdx.x;
    int tok0 = blockIdx.x * 32;
    if (tid < NE) lcnt[tid] = 0;
    for (int idx = tid; idx < 32*DIM; idx += 256)
        hs[idx] = h[(size_t)tok0*DIM + idx];
    __syncthreads();
    int tl = tid >> 3, e = tid & 7;
    float acc = gb[e];
    const float* hrow = hs + tl*DIM;
    for (int d = 0; d < DIM; d += 4) {
        acc += hrow[d]   * gW[(d)  *NE + e] + hrow[d+1] * gW[(d+1)*NE + e]
             + hrow[d+2] * gW[(d+2)*NE + e] + hrow[d+3] * gW[(d+3)*NE + e];
    }
    lg[tl][e] = acc;
    __syncthreads();
    if (tid < 32) {
        int i0 = 0; float v0 = lg[tid][0];
#pragma unroll
        for (int k = 1; k < NE; ++k) { float v = lg[tid][k]; if (v > v0) { v0 = v; i0 = k; } }
        int i1 = -1; float v1 = -1e30f;
#pragma unroll
        for (int k = 0; k < NE; ++k) { float v = lg[tid][k]; if (k != i0 && v > v1) { v1 = v; i1 = k; } }
        float e1 = expf(v1 - v0);
        float w0 = 1.0f / (1.0f + e1);
        float w1 = e1 / (1.0f + e1);
        int token = tok0 + tid;
        e01[2*token] = i0; e01[2*token+1] = i1;
        w01[2*token] = w0; w01[2*token+1] = w1;
        atomicAdd(&lcnt[i0], 1);
        atomicAdd(&lcnt[i1], 1);
    }
    __syncthreads();
    if (tid < NE) atomicAdd(&counts[tid], lcnt[tid]);
}

__global__ void k_scan(const int* __restrict__ counts, int* __restrict__ offsets,
                       int* __restrict__ cursor) {
    int off = 0;
    for (int e = 0; e < NE; ++e) { offsets[e] = off; off += counts[e]; cursor[e] = 0; }
}

__global__ void k_scatter(const int* __restrict__ e01, const float* __restrict__ w01,
                          const int* __restrict__ offsets, int* __restrict__ cursor,
                          int* __restrict__ entryTok, float* __restrict__ entryW,
                          int* __restrict__ pos01) {
    __shared__ int lcnt[NE], lbase[NE];
    int tid = threadIdx.x;
    int token = blockIdx.x * 256 + tid;
    if (tid < NE) lcnt[tid] = 0;
    __syncthreads();
    int i0 = e01[2*token], i1 = e01[2*token+1];
    int li0 = atomicAdd(&lcnt[i0], 1);
    int li1 = atomicAdd(&lcnt[i1], 1);
    __syncthreads();
    if (tid < NE) lbase[tid] = atomicAdd(&cursor[tid], lcnt[tid]);
    __syncthreads();
    int p0 = offsets[i0] + lbase[i0] + li0;
    int p1 = offsets[i1] + lbase[i1] + li1;
    entryTok[p0] = token; entryW[p0] = w01[2*token];
    entryTok[p1] = token; entryW[p1] = w01[2*token+1];
    pos01[2*token] = p0; pos01[2*token+1] = p1;
}

// grouped expert GEMM: tile = TM tokens (one expert) x 240 outputs
// block = 64 threads; thread tid<60 owns f = 4*tid..4*tid+3; acc[16][4]
__global__ __launch_bounds__(64) void k_gemm(
        const float* __restrict__ h, const float* __restrict__ eW,
        const float* __restrict__ eb, const int* __restrict__ counts,
        const int* __restrict__ offsets, const int* __restrict__ entryTok,
        const float* __restrict__ entryW, float* __restrict__ tmp, int layer) {
    int e = blockIdx.y;
    int cnt = counts[e];
    int t0 = blockIdx.x * TM;
    if (t0 >= cnt) return;
    int nt = min(TM, cnt - t0);
    int base = offsets[e] + t0;
    __shared__ float hs[TM*DIM];
    __shared__ int stok[TM];
    __shared__ float sw[TM];
    int tid = threadIdx.x;
    if (tid < TM) {
        if (tid < nt) { stok[tid] = entryTok[base + tid]; sw[tid] = entryW[base + tid]; }
        else          { stok[tid] = 0;                    sw[tid] = 0.f; }
    }
    __syncthreads();
    for (int idx = tid; idx < TM*DIM; idx += 64) {
        int t = idx / DIM, d = idx - t*DIM;
        hs[idx] = (t < nt) ? h[(size_t)stok[t]*DIM + d] : 0.f;
    }
    __syncthreads();
    if (tid >= 60) return;

    const float* Wb = eW + ((size_t)(layer*NE + e))*DIM*DIM + 4*tid;
    float acc[TM][4];
#pragma unroll
    for (int t = 0; t < TM; ++t) { acc[t][0]=0.f; acc[t][1]=0.f; acc[t][2]=0.f; acc[t][3]=0.f; }

    for (int d0 = 0; d0 < DIM; d0 += 4) {
        float4 w0 = *(const float4*)(Wb + (size_t)(d0+0)*DIM);
        float4 w1 = *(const float4*)(Wb + (size_t)(d0+1)*DIM);
        float4 w2 = *(const float4*)(Wb + (size_t)(d0+2)*DIM);
        float4 w3 = *(const float4*)(Wb + (size_t)(d0+3)*DIM);
#pragma unroll
        for (int t = 0; t < TM; ++t) {
            float4 hv = *(const float4*)&hs[t*DIM + d0];
            acc[t][0] += hv.x*w0.x + hv.y*w1.x + hv.z*w2.x + hv.w*w3.x;
            acc[t][1] += hv.x*w0.y + hv.y*w1.y + hv.z*w2.y + hv.w*w3.y;
            acc[t][2] += hv.x*w0.z + hv.y*w1.z + hv.z*w2.z + hv.w*w3.z;
            acc[t][3] += hv.x*w0.w + hv.y*w1.w + hv.z*w2.w + hv.w*w3.w;
        }
    }

    const float* ebp = eb + ((size_t)(layer*NE + e))*DIM + 4*tid;
    float b0 = ebp[0], b1 = ebp[1], b2 = ebp[2], b3 = ebp[3];
    for (int t = 0; t < nt; ++t) {
        float w = sw[t];
        float4 o;
        o.x = (acc[t][0] + b0) * w;
        o.y = (acc[t][1] + b1) * w;
        o.z = (acc[t][2] + b2) * w;
        o.w = (acc[t][3] + b3) * w;
        *(float4*)(tmp + (size_t)(base + t)*DIM + 4*tid) = o;
    }
}

// combine two expert outputs + LayerNorm residual: h = y + LN(y)
// one wave (64 lanes) per token, 4 tokens per block
__global__ void k_combine(const float* __restrict__ tmp, const int* __restrict__ pos01,
                          const float* __restrict__ gamma, const float* __restrict__ beta,
                          float* __restrict__ h) {
    int token = blockIdx.x * 4 + (threadIdx.x >> 6);
    int lane = threadIdx.x & 63;
    int p0 = pos01[2*token], p1 = pos01[2*token+1];
    const float* a = tmp + (size_t)p0*DIM;
    const float* b = tmp + (size_t)p1*DIM;
    float v[4];
    float sum = 0.f;
#pragma unroll
    for (int j = 0; j < 4; ++j) {
        int d = lane + 64*j;
        float y = (d < DIM) ? (a[d] + b[d]) : 0.f;
        v[j] = y; sum += y;
    }
#pragma unroll
    for (int o = 32; o > 0; o >>= 1) sum += __shfl_xor(sum, o, 64);
    float mean = sum * (1.0f/DIM);
    float vs = 0.f;
#pragma unroll
    for (int j = 0; j < 4; ++j) {
        int d = lane + 64*j;
        if (d < DIM) { float t = v[j] - mean; vs += t*t; }
    }
#pragma unroll
    for (int o = 32; o > 0; o >>= 1) vs += __shfl_xor(vs, o, 64);
    float rs = rsqrtf(vs * (1.0f/DIM) + 1e-5f);
#pragma unroll
    for (int j = 0; j < 4; ++j) {
        int d = lane + 64*j;
        if (d < DIM)
            h[(size_t)token*DIM + d] = v[j] + (v[j] - mean) * rs * gamma[d] + beta[d];
    }
}

// pool: out_acc[b] += sum over chunk tokens of h . head_W
__global__ void k_pool(const float* __restrict__ h, const float* __restrict__ headW,
                       float* __restrict__ out_acc) {
    int b = blockIdx.x, chunk = blockIdx.y;
    int tid = threadIdx.x;
    float acc = 0.f;
    if (tid < DIM) {
        float hw = headW[tid];
        for (int s = 0; s < 64; ++s) {
            int tok = b*SS + chunk*64 + s;
            acc += h[(size_t)tok*DIM + tid] * hw;
        }
    }
    __shared__ float red[256];
    red[tid] = acc;
    __syncthreads();
    for (int o = 128; o > 0; o >>= 1) { if (tid < o) red[tid] += red[tid+o]; __syncthreads(); }
    if (tid == 0) atomicAdd(&out_acc[b], red[0]);
}

__global__ void k_final(const float* __restrict__ out_acc, const float* __restrict__ headb,
                        float* __restrict__ out) {
    int b = threadIdx.x;
    if (b < BB) {
        float z = out_acc[b] * (1.0f/SS) + headb[0];
        out[b] = 1.0f / (1.0f + expf(-z));
    }
}

// ---------------- launch ----------------
extern "C" void kernel_launch(void* const* d_in, const int* in_sizes, int n_in,
                              void* d_out, int out_size, void* d_ws, size_t ws_size,
                              hipStream_t stream) {
    const float* x     = (const float*)d_in[0];
    const int*   step  = (const int*)  d_in[1];
    const float* roots = (const float*)d_in[2];
    const float* projW = (const float*)d_in[3];
    const float* gateW = (const float*)d_in[4];
    const float* gateb = (const float*)d_in[5];
    const float* eW    = (const float*)d_in[6];
    const float* eb    = (const float*)d_in[7];
    const float* gamma = (const float*)d_in[8];
    const float* beta  = (const float*)d_in[9];
    const float* headW = (const float*)d_in[10];
    const float* headb = (const float*)d_in[11];
    float* out = (float*)d_out;

    char* w = (char*)d_ws;
    float* cosT    = (float*)(w + OFF_COST);
    float* sinT    = (float*)(w + OFF_SINT);
    float* h       = (float*)(w + OFF_H);
    float* tmp     = (float*)(w + OFF_TMP);
    float* w01     = (float*)(w + OFF_W01);
    float* entryW  = (float*)(w + OFF_ENTW);
    float* out_acc = (float*)(w + OFF_OUTACC);
    int*   e01     = (int*)  (w + OFF_E01);
    int*   pos01   = (int*)  (w + OFF_POS01);
    int*   entryTok= (int*)  (w + OFF_ENTTOK);
    int*   counts  = (int*)  (w + OFF_COUNTS);
    int*   offs    = (int*)  (w + OFF_OFFS);
    int*   cursor  = (int*)  (w + OFF_CURSOR);

    k_tables<<<240, 256, 0, stream>>>(roots, projW, cosT, sinT);
    k_cycle<<<NTOK, 256, 0, stream>>>(x, step, cosT, sinT, h);

    for (int l = 0; l < DEPTH; ++l) {
        hipMemsetAsync(counts, 0, NE*sizeof(int), stream);
        k_gate<<<NTOK/32, 256, 0, stream>>>(h, gateW + (size_t)l*DIM*NE, gateb + l*NE,
                                            e01, w01, counts);
        k_scan<<<1, 1, 0, stream>>>(counts, offs, cursor);
        k_scatter<<<NTOK/256, 256, 0, stream>>>(e01, w01, offs, cursor,
                                                entryTok, entryW, pos01);
        k_gemm<<<dim3(NTOK/TM, NE), 64, 0, stream>>>(h, eW, eb, counts, offs,
                                                     entryTok, entryW, tmp, l);
        k_combine<<<NTOK/4, 256, 0, stream>>>(tmp, pos01, gamma, beta, h);
    }

    hipMemsetAsync(out_acc, 0, BB*sizeof(float), stream);
    k_pool<<<dim3(BB, 32), 256, 0, stream>>>(h, headW, out_acc);
    k_final<<<1, 64, 0, stream>>>(out_acc, headb, out);
}

// Round 2
// 627.484 us; speedup vs baseline: 2.1377x; 2.1377x over previous
//
#include <hip/hip_runtime.h>
#include <math.h>

#define DIM 240
#define NE 8
#define DEPTH 8
#define BB 8
#define SS 2048
#define NTOK (BB * SS)
#define NENT (2 * NTOK)
#define TWO_PI 6.28318530717958647692f

typedef __attribute__((ext_vector_type(8))) short s16x8;
typedef __attribute__((ext_vector_type(4))) float f32x4;

// ---------------- workspace layout (byte offsets, 256-aligned) ----------------
#define ALIGN256(x) (((x) + 255) & ~((size_t)255))
static const size_t OFF_COST   = 0;                                        // 240*240 f
static const size_t OFF_SINT   = ALIGN256(OFF_COST  + 240*240*4);          // 240*240 f
static const size_t OFF_H      = ALIGN256(OFF_SINT  + 240*240*4);          // NTOK*DIM f
static const size_t OFF_TMP    = ALIGN256(OFF_H     + (size_t)NTOK*DIM*4); // NENT*DIM f
static const size_t OFF_W01    = ALIGN256(OFF_TMP   + (size_t)NENT*DIM*4); // 2*NTOK f
static const size_t OFF_ENTW   = ALIGN256(OFF_W01   + 2*NTOK*4);           // NENT f
static const size_t OFF_OUTACC = ALIGN256(OFF_ENTW  + NENT*4);             // 8 f
static const size_t OFF_E01    = ALIGN256(OFF_OUTACC + 8*4);               // 2*NTOK i
static const size_t OFF_POS01  = ALIGN256(OFF_E01    + 2*NTOK*4);          // 2*NTOK i
static const size_t OFF_ENTTOK = ALIGN256(OFF_POS01  + 2*NTOK*4);          // NENT i
static const size_t OFF_COUNTS = ALIGN256(OFF_ENTTOK + NENT*4);            // 8 i
static const size_t OFF_OFFS   = ALIGN256(OFF_COUNTS + 8*4);               // 8 i
static const size_t OFF_CURSOR = ALIGN256(OFF_OFFS   + 8*4);               // 8 i
// packed bf16 expert weights: 64 experts x [kstep 8][tile 15][lane 64][j 8] bf16
static const size_t WPACK_PER_E = 8 * 15 * 64 * 8;                         // elements
static const size_t OFF_WPACK  = ALIGN256(OFF_CURSOR + 8*4);               // 64*WPACK_PER_E shorts

__device__ inline short f2bf(float x) {
    unsigned u = __builtin_bit_cast(unsigned, x);
    u += 0x7fffu + ((u >> 16) & 1u);   // RNE
    return (short)(u >> 16);
}

// ---------------- kernels ----------------

__global__ void k_tables(const float* __restrict__ roots, const float* __restrict__ projW,
                         float* __restrict__ cosT, float* __restrict__ sinT) {
    int s = blockIdx.x;
    int d = threadIdx.x;
    if (d >= DIM) return;
    int j = d % 80;
    float acc = 0.f;
#pragma unroll
    for (int r = 0; r < 8; ++r) acc += roots[s*8 + r] * projW[r*80 + j];
    cosT[s*DIM + d] = cosf(acc);
    sinT[s*DIM + d] = sinf(acc);
}

__global__ void k_cycle(const float* __restrict__ x, const int* __restrict__ step,
                        const float* __restrict__ cosT, const float* __restrict__ sinT,
                        float* __restrict__ h) {
    int tok = blockIdx.x;
    int d = threadIdx.x;
    if (d >= DIM) return;
    int s = tok % SS;
    int sm = s % 240;
    float pump = 0.8f * sinf((float)step[0] * 0.006f * TWO_PI);
    const float* xr = x + (size_t)tok * DIM;
    const float* cr = cosT + sm * DIM;
    const float* sr = sinT + sm * DIM;
    int dm1 = (d + DIM - 1) % DIM;
    int dm2 = (d + DIM - 2) % DIM;
    float x1d  = xr[d]   * (cr[d]   + pump);
    float x1m1 = xr[dm1] * (cr[dm1] + pump);
    float x1m2 = xr[dm2] * (cr[dm2] + pump);
    float x2d  = x1m1 * sr[d];
    float x2m1 = x1m2 * sr[dm1];
    float x3d  = x2m1 * cr[d];
    h[(size_t)tok*DIM + d] = (x1d + x2d + x3d) * (1.0f/3.0f);
}

// pack expert weights into MFMA B-fragment layout, fp32 -> bf16, K padded to 256
// Wpack[eg][kstep][tile][lane][j] : holds W[d = kstep*32 + (lane>>4)*8 + j][f = tile*16 + (lane&15)]
__global__ __launch_bounds__(64) void k_pack(const float* __restrict__ eW, short* __restrict__ wp) {
    int tile = blockIdx.x;   // 0..14
    int ks   = blockIdx.y;   // 0..7
    int eg   = blockIdx.z;   // 0..63 (layer*8+expert)
    int lane = threadIdx.x;
    int f  = tile*16 + (lane & 15);
    int d0 = ks*32 + (lane >> 4)*8;
    const float* W = eW + (size_t)eg*DIM*DIM;
    short v[8];
#pragma unroll
    for (int j = 0; j < 8; ++j) {
        int d = d0 + j;
        v[j] = (d < DIM) ? f2bf(W[(size_t)d*DIM + f]) : (short)0;
    }
    s16x8* dst = (s16x8*)(wp + ((size_t)eg*8*15 + (size_t)ks*15 + tile)*512 + lane*8);
    *dst = *(s16x8*)v;
}

// gate: logits = h @ gW + gb; softmax; top2; counts
__global__ void k_gate(const float* __restrict__ h, const float* __restrict__ gW,
                       const float* __restrict__ gb, int* __restrict__ e01,
                       float* __restrict__ w01, int* __restrict__ counts) {
    __shared__ float hs[32*DIM];
    __shared__ float lg[32][NE];
    __shared__ int lcnt[NE];
    int tid = threadIdx.x;
    int tok0 = blockIdx.x * 32;
    if (tid < NE) lcnt[tid] = 0;
    for (int idx = tid; idx < 32*DIM; idx += 256)
        hs[idx] = h[(size_t)tok0*DIM + idx];
    __syncthreads();
    int tl = tid >> 3, e = tid & 7;
    float acc = gb[e];
    const float* hrow = hs + tl*DIM;
    for (int d = 0; d < DIM; d += 4) {
        acc += hrow[d]   * gW[(d)  *NE + e] + hrow[d+1] * gW[(d+1)*NE + e]
             + hrow[d+2] * gW[(d+2)*NE + e] + hrow[d+3] * gW[(d+3)*NE + e];
    }
    lg[tl][e] = acc;
    __syncthreads();
    if (tid < 32) {
        int i0 = 0; float v0 = lg[tid][0];
#pragma unroll
        for (int k = 1; k < NE; ++k) { float v = lg[tid][k]; if (v > v0) { v0 = v; i0 = k; } }
        int i1 = -1; float v1 = -1e30f;
#pragma unroll
        for (int k = 0; k < NE; ++k) { float v = lg[tid][k]; if (k != i0 && v > v1) { v1 = v; i1 = k; } }
        float e1 = expf(v1 - v0);
        float w0 = 1.0f / (1.0f + e1);
        float w1 = e1 / (1.0f + e1);
        int token = tok0 + tid;
        e01[2*token] = i0; e01[2*token+1] = i1;
        w01[2*token] = w0; w01[2*token+1] = w1;
        atomicAdd(&lcnt[i0], 1);
        atomicAdd(&lcnt[i1], 1);
    }
    __syncthreads();
    if (tid < NE) atomicAdd(&counts[tid], lcnt[tid]);
}

__global__ void k_scan(const int* __restrict__ counts, int* __restrict__ offsets,
                       int* __restrict__ cursor) {
    int off = 0;
    for (int e = 0; e < NE; ++e) { offsets[e] = off; off += counts[e]; cursor[e] = 0; }
}

__global__ void k_scatter(const int* __restrict__ e01, const float* __restrict__ w01,
                          const int* __restrict__ offsets, int* __restrict__ cursor,
                          int* __restrict__ entryTok, float* __restrict__ entryW,
                          int* __restrict__ pos01) {
    __shared__ int lcnt[NE], lbase[NE];
    int tid = threadIdx.x;
    int token = blockIdx.x * 256 + tid;
    if (tid < NE) lcnt[tid] = 0;
    __syncthreads();
    int i0 = e01[2*token], i1 = e01[2*token+1];
    int li0 = atomicAdd(&lcnt[i0], 1);
    int li1 = atomicAdd(&lcnt[i1], 1);
    __syncthreads();
    if (tid < NE) lbase[tid] = atomicAdd(&cursor[tid], lcnt[tid]);
    __syncthreads();
    int p0 = offsets[i0] + lbase[i0] + li0;
    int p1 = offsets[i1] + lbase[i1] + li1;
    entryTok[p0] = token; entryW[p0] = w01[2*token];
    entryTok[p1] = token; entryW[p1] = w01[2*token+1];
    pos01[2*token] = p0; pos01[2*token+1] = p1;
}

// grouped expert GEMM via MFMA: block = 64 tokens (one expert) x 240 outputs,
// 256 threads = 4 waves, each wave does 16 tokens x 15 N-tiles, K=256 (padded)
__global__ __launch_bounds__(256) void k_gemm(
        const float* __restrict__ h, const short* __restrict__ wp,
        const float* __restrict__ eb, const int* __restrict__ counts,
        const int* __restrict__ offsets, const int* __restrict__ entryTok,
        const float* __restrict__ entryW, float* __restrict__ tmp, int layer) {
    int e = blockIdx.y;
    int cnt = counts[e];
    int t0 = blockIdx.x * 64;
    if (t0 >= cnt) return;
    int nt = min(64, cnt - t0);
    int base = offsets[e] + t0;

    __shared__ short As[64*264];   // 64 tokens x 256(K,padded)+8(bank pad) bf16
    __shared__ float sw[64];
    __shared__ int stok[64];
    int tid = threadIdx.x;
    if (tid < 64) {
        if (tid < nt) { stok[tid] = entryTok[base+tid]; sw[tid] = entryW[base+tid]; }
        else          { stok[tid] = 0;                  sw[tid] = 0.f; }
    }
    __syncthreads();
    // stage h (fp32) -> bf16 LDS rows
    for (int idx = tid; idx < 64*60; idx += 256) {
        int row = idx / 60, c4 = idx - row*60;
        float4 v = *(const float4*)(h + (size_t)stok[row]*DIM + c4*4);
        short q[4];
        q[0] = f2bf(v.x); q[1] = f2bf(v.y); q[2] = f2bf(v.z); q[3] = f2bf(v.w);
        *(short4*)(As + row*264 + c4*4) = *(short4*)q;
    }
    for (int idx = tid; idx < 64*16; idx += 256) {   // zero K pad 240..255
        int row = idx >> 4, c = 240 + (idx & 15);
        As[row*264 + c] = 0;
    }
    __syncthreads();

    int wave = tid >> 6, lane = tid & 63;
    int row0 = wave * 16;
    f32x4 acc[15];
#pragma unroll
    for (int t = 0; t < 15; ++t) acc[t] = (f32x4){0.f, 0.f, 0.f, 0.f};

    const short* abase = As + (row0 + (lane & 15))*264 + (lane >> 4)*8;
    const short* wbase = wp + (size_t)(layer*NE + e)*WPACK_PER_E + lane*8;

    for (int ks = 0; ks < 8; ++ks) {
        s16x8 af = *(const s16x8*)(abase + ks*32);
#pragma unroll
        for (int t = 0; t < 15; ++t) {
            s16x8 bf = *(const s16x8*)(wbase + ((size_t)ks*15 + t)*512);
            acc[t] = __builtin_amdgcn_mfma_f32_16x16x32_bf16(af, bf, acc[t], 0, 0, 0);
        }
    }

    // epilogue: D layout col = lane&15, row = (lane>>4)*4 + r
    const float* ebp = eb + (size_t)(layer*NE + e)*DIM;
    int mr = row0 + (lane >> 4)*4;
#pragma unroll
    for (int t = 0; t < 15; ++t) {
        int n = t*16 + (lane & 15);
        float bias = ebp[n];
#pragma unroll
        for (int r = 0; r < 4; ++r) {
            int row = mr + r;
            if (row < nt)
                tmp[(size_t)(base + row)*DIM + n] = (acc[t][r] + bias) * sw[row];
        }
    }
}

// combine two expert outputs + LayerNorm residual: h = y + LN(y)
__global__ void k_combine(const float* __restrict__ tmp, const int* __restrict__ pos01,
                          const float* __restrict__ gamma, const float* __restrict__ beta,
                          float* __restrict__ h) {
    int token = blockIdx.x * 4 + (threadIdx.x >> 6);
    int lane = threadIdx.x & 63;
    int p0 = pos01[2*token], p1 = pos01[2*token+1];
    const float* a = tmp + (size_t)p0*DIM;
    const float* b = tmp + (size_t)p1*DIM;
    float v[4];
    float sum = 0.f;
#pragma unroll
    for (int j = 0; j < 4; ++j) {
        int d = lane + 64*j;
        float y = (d < DIM) ? (a[d] + b[d]) : 0.f;
        v[j] = y; sum += y;
    }
#pragma unroll
    for (int o = 32; o > 0; o >>= 1) sum += __shfl_xor(sum, o, 64);
    float mean = sum * (1.0f/DIM);
    float vs = 0.f;
#pragma unroll
    for (int j = 0; j < 4; ++j) {
        int d = lane + 64*j;
        if (d < DIM) { float t = v[j] - mean; vs += t*t; }
    }
#pragma unroll
    for (int o = 32; o > 0; o >>= 1) vs += __shfl_xor(vs, o, 64);
    float rs = rsqrtf(vs * (1.0f/DIM) + 1e-5f);
#pragma unroll
    for (int j = 0; j < 4; ++j) {
        int d = lane + 64*j;
        if (d < DIM)
            h[(size_t)token*DIM + d] = v[j] + (v[j] - mean) * rs * gamma[d] + beta[d];
    }
}

__global__ void k_pool(const float* __restrict__ h, const float* __restrict__ headW,
                       float* __restrict__ out_acc) {
    int b = blockIdx.x, chunk = blockIdx.y;
    int tid = threadIdx.x;
    float acc = 0.f;
    if (tid < DIM) {
        float hw = headW[tid];
        for (int s = 0; s < 64; ++s) {
            int tok = b*SS + chunk*64 + s;
            acc += h[(size_t)tok*DIM + tid] * hw;
        }
    }
    __shared__ float red[256];
    red[tid] = acc;
    __syncthreads();
    for (int o = 128; o > 0; o >>= 1) { if (tid < o) red[tid] += red[tid+o]; __syncthreads(); }
    if (tid == 0) atomicAdd(&out_acc[b], red[0]);
}

__global__ void k_final(const float* __restrict__ out_acc, const float* __restrict__ headb,
                        float* __restrict__ out) {
    int b = threadIdx.x;
    if (b < BB) {
        float z = out_acc[b] * (1.0f/SS) + headb[0];
        out[b] = 1.0f / (1.0f + expf(-z));
    }
}

// ---------------- launch ----------------
extern "C" void kernel_launch(void* const* d_in, const int* in_sizes, int n_in,
                              void* d_out, int out_size, void* d_ws, size_t ws_size,
                              hipStream_t stream) {
    const float* x     = (const float*)d_in[0];
    const int*   step  = (const int*)  d_in[1];
    const float* roots = (const float*)d_in[2];
    const float* projW = (const float*)d_in[3];
    const float* gateW = (const float*)d_in[4];
    const float* gateb = (const float*)d_in[5];
    const float* eW    = (const float*)d_in[6];
    const float* eb    = (const float*)d_in[7];
    const float* gamma = (const float*)d_in[8];
    const float* beta  = (const float*)d_in[9];
    const float* headW = (const float*)d_in[10];
    const float* headb = (const float*)d_in[11];
    float* out = (float*)d_out;

    char* w = (char*)d_ws;
    float* cosT    = (float*)(w + OFF_COST);
    float* sinT    = (float*)(w + OFF_SINT);
    float* h       = (float*)(w + OFF_H);
    float* tmp     = (float*)(w + OFF_TMP);
    float* w01     = (float*)(w + OFF_W01);
    float* entryW  = (float*)(w + OFF_ENTW);
    float* out_acc = (float*)(w + OFF_OUTACC);
    int*   e01     = (int*)  (w + OFF_E01);
    int*   pos01   = (int*)  (w + OFF_POS01);
    int*   entryTok= (int*)  (w + OFF_ENTTOK);
    int*   counts  = (int*)  (w + OFF_COUNTS);
    int*   offs    = (int*)  (w + OFF_OFFS);
    int*   cursor  = (int*)  (w + OFF_CURSOR);
    short* wpack   = (short*)(w + OFF_WPACK);

    k_tables<<<240, 256, 0, stream>>>(roots, projW, cosT, sinT);
    k_pack<<<dim3(15, 8, 64), 64, 0, stream>>>(eW, wpack);
    k_cycle<<<NTOK, 256, 0, stream>>>(x, step, cosT, sinT, h);

    for (int l = 0; l < DEPTH; ++l) {
        hipMemsetAsync(counts, 0, NE*sizeof(int), stream);
        k_gate<<<NTOK/32, 256, 0, stream>>>(h, gateW + (size_t)l*DIM*NE, gateb + l*NE,
                                            e01, w01, counts);
        k_scan<<<1, 1, 0, stream>>>(counts, offs, cursor);
        k_scatter<<<NTOK/256, 256, 0, stream>>>(e01, w01, offs, cursor,
                                                entryTok, entryW, pos01);
        k_gemm<<<dim3(NENT/64, NE), 256, 0, stream>>>(h, wpack, eb, counts, offs,
                                                      entryTok, entryW, tmp, l);
        k_combine<<<NTOK/4, 256, 0, stream>>>(tmp, pos01, gamma, beta, h);
    }

    hipMemsetAsync(out_acc, 0, BB*sizeof(float), stream);
    k_pool<<<dim3(BB, 32), 256, 0, stream>>>(h, headW, out_acc);
    k_final<<<1, 64, 0, stream>>>(out_acc, headb, out);
}

// Round 4
// 581.552 us; speedup vs baseline: 2.3065x; 1.0790x over previous
//
#include <hip/hip_runtime.h>
#include <math.h>

#define DIM 240
#define NE 8
#define DEPTH 8
#define BB 8
#define SS 2048
#define NTOK (BB * SS)
#define NENT (2 * NTOK)
#define TWO_PI 6.28318530717958647692f

typedef __attribute__((ext_vector_type(8))) short s16x8;
typedef __attribute__((ext_vector_type(4))) float f32x4;

// ---------------- workspace layout (byte offsets, 256-aligned) ----------------
#define ALIGN256(x) (((x) + 255) & ~((size_t)255))
static const size_t OFF_COST   = 0;                                        // 240*240 f
static const size_t OFF_SINT   = ALIGN256(OFF_COST  + 240*240*4);          // 240*240 f
static const size_t OFF_H      = ALIGN256(OFF_SINT  + 240*240*4);          // NTOK*DIM f
static const size_t OFF_TMP    = ALIGN256(OFF_H     + (size_t)NTOK*DIM*4); // NE*NTOK*DIM f
static const size_t OFF_ENTW   = ALIGN256(OFF_TMP   + (size_t)NE*NTOK*DIM*4); // NE*NTOK f
static const size_t OFF_OUTACC = ALIGN256(OFF_ENTW  + (size_t)NE*NTOK*4);  // 8 f
static const size_t OFF_POS01  = ALIGN256(OFF_OUTACC + 8*4);               // 2*NTOK i
static const size_t OFF_ENTTOK = ALIGN256(OFF_POS01  + 2*NTOK*4);          // NE*NTOK i
static const size_t OFF_CURSOR = ALIGN256(OFF_ENTTOK + (size_t)NE*NTOK*4); // 64 i (DEPTH*NE)
// packed bf16 expert weights: 64 experts x [kstep 8][tile 15][lane 64][j 8] bf16
static const size_t WPACK_PER_E = 8 * 15 * 64 * 8;                         // elements
static const size_t OFF_WPACK  = ALIGN256(OFF_CURSOR + 64*4);

__device__ inline short f2bf(float x) {
    unsigned u = __builtin_bit_cast(unsigned, x);
    u += 0x7fffu + ((u >> 16) & 1u);   // RNE
    return (short)(u >> 16);
}

// ---------------- kernels ----------------

__global__ void k_init(int* __restrict__ cursor, float* __restrict__ out_acc) {
    int t = threadIdx.x;
    if (t < DEPTH*NE) cursor[t] = 0;
    if (t < BB) out_acc[t] = 0.f;
}

__global__ void k_tables(const float* __restrict__ roots, const float* __restrict__ projW,
                         float* __restrict__ cosT, float* __restrict__ sinT) {
    int s = blockIdx.x;
    int d = threadIdx.x;
    if (d >= DIM) return;
    int j = d % 80;
    float acc = 0.f;
#pragma unroll
    for (int r = 0; r < 8; ++r) acc += roots[s*8 + r] * projW[r*80 + j];
    cosT[s*DIM + d] = cosf(acc);
    sinT[s*DIM + d] = sinf(acc);
}

__global__ void k_cycle(const float* __restrict__ x, const int* __restrict__ step,
                        const float* __restrict__ cosT, const float* __restrict__ sinT,
                        float* __restrict__ h) {
    int tok = blockIdx.x;
    int d = threadIdx.x;
    if (d >= DIM) return;
    int s = tok % SS;
    int sm = s % 240;
    float pump = 0.8f * sinf((float)step[0] * 0.006f * TWO_PI);
    const float* xr = x + (size_t)tok * DIM;
    const float* cr = cosT + sm * DIM;
    const float* sr = sinT + sm * DIM;
    int dm1 = (d + DIM - 1) % DIM;
    int dm2 = (d + DIM - 2) % DIM;
    float x1d  = xr[d]   * (cr[d]   + pump);
    float x1m1 = xr[dm1] * (cr[dm1] + pump);
    float x1m2 = xr[dm2] * (cr[dm2] + pump);
    float x2d  = x1m1 * sr[d];
    float x2m1 = x1m2 * sr[dm1];
    float x3d  = x2m1 * cr[d];
    h[(size_t)tok*DIM + d] = (x1d + x2d + x3d) * (1.0f/3.0f);
}

// pack expert weights into MFMA B-fragment layout, fp32 -> bf16, K padded to 256
__global__ __launch_bounds__(64) void k_pack(const float* __restrict__ eW, short* __restrict__ wp) {
    int tile = blockIdx.x;   // 0..14
    int ks   = blockIdx.y;   // 0..7
    int eg   = blockIdx.z;   // 0..63
    int lane = threadIdx.x;
    int f  = tile*16 + (lane & 15);
    int d0 = ks*32 + (lane >> 4)*8;
    const float* W = eW + (size_t)eg*DIM*DIM;
    short v[8];
#pragma unroll
    for (int j = 0; j < 8; ++j) {
        int d = d0 + j;
        v[j] = (d < DIM) ? f2bf(W[(size_t)d*DIM + f]) : (short)0;
    }
    s16x8* dst = (s16x8*)(wp + ((size_t)eg*8*15 + (size_t)ks*15 + tile)*512 + lane*8);
    *dst = *(s16x8*)v;
}

// fused gate + softmax-top2 + scatter (capacity bucketing, no scan)
// block = 64 tokens, 256 threads
__global__ __launch_bounds__(256) void k_gatescatter(
        const float* __restrict__ h, const float* __restrict__ gW,
        const float* __restrict__ gb, int* __restrict__ cursor,
        int* __restrict__ entryTok, float* __restrict__ entryW,
        int* __restrict__ pos01) {
    __shared__ float hs[64*DIM];      // 61440 B
    __shared__ float lg[64][NE];      // 2048 B
    __shared__ int   le01[64];        // e0 | e1<<8
    __shared__ int   lli01[64];       // li0 | li1<<16
    __shared__ float lw[64][2];
    __shared__ int   lcnt[NE], lbase[NE];
    int tid = threadIdx.x;
    int tok0 = blockIdx.x * 64;
    if (tid < NE) lcnt[tid] = 0;
    const float4* hsrc = (const float4*)(h + (size_t)tok0*DIM);
    float4* hdst = (float4*)hs;
#pragma unroll
    for (int i = 0; i < 15; ++i) hdst[tid + 256*i] = hsrc[tid + 256*i];
    __syncthreads();
#pragma unroll
    for (int i = 0; i < 2; ++i) {
        int tt = tid + 256*i;
        int tl = tt >> 3, e = tt & 7;
        const float* hrow = hs + tl*DIM;
        float acc = gb[e];
        for (int d = 0; d < DIM; d += 4) {
            acc += hrow[d]   * gW[(d)  *NE + e] + hrow[d+1] * gW[(d+1)*NE + e]
                 + hrow[d+2] * gW[(d+2)*NE + e] + hrow[d+3] * gW[(d+3)*NE + e];
        }
        lg[tl][e] = acc;
    }
    __syncthreads();
    if (tid < 64) {
        int i0 = 0; float v0 = lg[tid][0];
#pragma unroll
        for (int k = 1; k < NE; ++k) { float v = lg[tid][k]; if (v > v0) { v0 = v; i0 = k; } }
        int i1 = -1; float v1 = -1e30f;
#pragma unroll
        for (int k = 0; k < NE; ++k) { float v = lg[tid][k]; if (k != i0 && v > v1) { v1 = v; i1 = k; } }
        float e1 = expf(v1 - v0);
        lw[tid][0] = 1.0f / (1.0f + e1);
        lw[tid][1] = e1 / (1.0f + e1);
        le01[tid] = i0 | (i1 << 8);
        int li0 = atomicAdd(&lcnt[i0], 1);
        int li1 = atomicAdd(&lcnt[i1], 1);
        lli01[tid] = li0 | (li1 << 16);
    }
    __syncthreads();
    if (tid < NE) lbase[tid] = atomicAdd(&cursor[tid], lcnt[tid]);
    __syncthreads();
    if (tid < 64) {
        int token = tok0 + tid;
        int i0 = le01[tid] & 0xff, i1 = le01[tid] >> 8;
        int p0 = i0*NTOK + lbase[i0] + (lli01[tid] & 0xffff);
        int p1 = i1*NTOK + lbase[i1] + (lli01[tid] >> 16);
        entryTok[p0] = token; entryW[p0] = lw[tid][0];
        entryTok[p1] = token; entryW[p1] = lw[tid][1];
        pos01[2*token] = p0; pos01[2*token+1] = p1;
    }
}

// grouped expert GEMM via MFMA: block = 64 tokens (one expert) x 240 outputs
__global__ __launch_bounds__(256) void k_gemm(
        const float* __restrict__ h, const short* __restrict__ wp,
        const float* __restrict__ eb, const int* __restrict__ cursor,
        const int* __restrict__ entryTok, const float* __restrict__ entryW,
        float* __restrict__ tmp, int layer) {
    int e = blockIdx.y;
    int cnt = cursor[e];
    int t0 = blockIdx.x * 64;
    if (t0 >= cnt) return;
    int nt = min(64, cnt - t0);
    size_t base = (size_t)e*NTOK + t0;

    __shared__ short As[64*264];
    __shared__ float sw[64];
    __shared__ int stok[64];
    int tid = threadIdx.x;
    if (tid < 64) {
        if (tid < nt) { stok[tid] = entryTok[base+tid]; sw[tid] = entryW[base+tid]; }
        else          { stok[tid] = 0;                  sw[tid] = 0.f; }
    }
    __syncthreads();
    for (int idx = tid; idx < 64*60; idx += 256) {
        int row = idx / 60, c4 = idx - row*60;
        float4 v = *(const float4*)(h + (size_t)stok[row]*DIM + c4*4);
        short q[4];
        q[0] = f2bf(v.x); q[1] = f2bf(v.y); q[2] = f2bf(v.z); q[3] = f2bf(v.w);
        *(short4*)(As + row*264 + c4*4) = *(short4*)q;
    }
    for (int idx = tid; idx < 64*16; idx += 256) {
        int row = idx >> 4, c = 240 + (idx & 15);
        As[row*264 + c] = 0;
    }
    __syncthreads();

    int wave = tid >> 6, lane = tid & 63;
    int row0 = wave * 16;
    f32x4 acc[15];
#pragma unroll
    for (int t = 0; t < 15; ++t) acc[t] = (f32x4){0.f, 0.f, 0.f, 0.f};

    const short* abase = As + (row0 + (lane & 15))*264 + (lane >> 4)*8;
    const short* wbase = wp + (size_t)(layer*NE + e)*WPACK_PER_E + lane*8;

    for (int ks = 0; ks < 8; ++ks) {
        s16x8 af = *(const s16x8*)(abase + ks*32);
#pragma unroll
        for (int t = 0; t < 15; ++t) {
            s16x8 bf = *(const s16x8*)(wbase + ((size_t)ks*15 + t)*512);
            acc[t] = __builtin_amdgcn_mfma_f32_16x16x32_bf16(af, bf, acc[t], 0, 0, 0);
        }
    }

    const float* ebp = eb + (size_t)(layer*NE + e)*DIM;
    int mr = row0 + (lane >> 4)*4;
#pragma unroll
    for (int t = 0; t < 15; ++t) {
        int n = t*16 + (lane & 15);
        float bias = ebp[n];
#pragma unroll
        for (int r = 0; r < 4; ++r) {
            int row = mr + r;
            if (row < nt)
                tmp[(base + row)*DIM + n] = (acc[t][r] + bias) * sw[row];
        }
    }
}

// combine two expert outputs + LayerNorm residual: h = y + LN(y)
__global__ void k_combine(const float* __restrict__ tmp, const int* __restrict__ pos01,
                          const float* __restrict__ gamma, const float* __restrict__ beta,
                          float* __restrict__ h) {
    int token = blockIdx.x * 4 + (threadIdx.x >> 6);
    int lane = threadIdx.x & 63;
    int p0 = pos01[2*token], p1 = pos01[2*token+1];
    const float* a = tmp + (size_t)p0*DIM;
    const float* b = tmp + (size_t)p1*DIM;
    float v[4];
    float sum = 0.f;
#pragma unroll
    for (int j = 0; j < 4; ++j) {
        int d = lane + 64*j;
        float y = (d < DIM) ? (a[d] + b[d]) : 0.f;
        v[j] = y; sum += y;
    }
#pragma unroll
    for (int o = 32; o > 0; o >>= 1) sum += __shfl_xor(sum, o, 64);
    float mean = sum * (1.0f/DIM);
    float vs = 0.f;
#pragma unroll
    for (int j = 0; j < 4; ++j) {
        int d = lane + 64*j;
        if (d < DIM) { float t = v[j] - mean; vs += t*t; }
    }
#pragma unroll
    for (int o = 32; o > 0; o >>= 1) vs += __shfl_xor(vs, o, 64);
    float rs = rsqrtf(vs * (1.0f/DIM) + 1e-5f);
#pragma unroll
    for (int j = 0; j < 4; ++j) {
        int d = lane + 64*j;
        if (d < DIM)
            h[(size_t)token*DIM + d] = v[j] + (v[j] - mean) * rs * gamma[d] + beta[d];
    }
}

__global__ void k_pool(const float* __restrict__ h, const float* __restrict__ headW,
                       float* __restrict__ out_acc) {
    int b = blockIdx.x, chunk = blockIdx.y;
    int tid = threadIdx.x;
    float acc = 0.f;
    if (tid < DIM) {
        float hw = headW[tid];
        for (int s = 0; s < 64; ++s) {
            int tok = b*SS + chunk*64 + s;
            acc += h[(size_t)tok*DIM + tid] * hw;
        }
    }
    __shared__ float red[256];
    red[tid] = acc;
    __syncthreads();
    for (int o = 128; o > 0; o >>= 1) { if (tid < o) red[tid] += red[tid+o]; __syncthreads(); }
    if (tid == 0) atomicAdd(&out_acc[b], red[0]);
}

__global__ void k_final(const float* __restrict__ out_acc, const float* __restrict__ headb,
                        float* __restrict__ out) {
    int b = threadIdx.x;
    if (b < BB) {
        float z = out_acc[b] * (1.0f/SS) + headb[0];
        out[b] = 1.0f / (1.0f + expf(-z));
    }
}

// ---------------- launch ----------------
extern "C" void kernel_launch(void* const* d_in, const int* in_sizes, int n_in,
                              void* d_out, int out_size, void* d_ws, size_t ws_size,
                              hipStream_t stream) {
    const float* x     = (const float*)d_in[0];
    const int*   step  = (const int*)  d_in[1];
    const float* roots = (const float*)d_in[2];
    const float* projW = (const float*)d_in[3];
    const float* gateW = (const float*)d_in[4];
    const float* gateb = (const float*)d_in[5];
    const float* eW    = (const float*)d_in[6];
    const float* eb    = (const float*)d_in[7];
    const float* gamma = (const float*)d_in[8];
    const float* beta  = (const float*)d_in[9];
    const float* headW = (const float*)d_in[10];
    const float* headb = (const float*)d_in[11];
    float* out = (float*)d_out;

    char* w = (char*)d_ws;
    float* cosT    = (float*)(w + OFF_COST);
    float* sinT    = (float*)(w + OFF_SINT);
    float* h       = (float*)(w + OFF_H);
    float* tmp     = (float*)(w + OFF_TMP);
    float* entryW  = (float*)(w + OFF_ENTW);
    float* out_acc = (float*)(w + OFF_OUTACC);
    int*   pos01   = (int*)  (w + OFF_POS01);
    int*   entryTok= (int*)  (w + OFF_ENTTOK);
    int*   cursor  = (int*)  (w + OFF_CURSOR);
    short* wpack   = (short*)(w + OFF_WPACK);

    k_init<<<1, 128, 0, stream>>>(cursor, out_acc);
    k_tables<<<240, 256, 0, stream>>>(roots, projW, cosT, sinT);
    k_pack<<<dim3(15, 8, 64), 64, 0, stream>>>(eW, wpack);
    k_cycle<<<NTOK, 256, 0, stream>>>(x, step, cosT, sinT, h);

    for (int l = 0; l < DEPTH; ++l) {
        k_gatescatter<<<NTOK/64, 256, 0, stream>>>(h, gateW + (size_t)l*DIM*NE,
                                                   gateb + l*NE, cursor + l*NE,
                                                   entryTok, entryW, pos01);
        k_gemm<<<dim3(NTOK/64, NE), 256, 0, stream>>>(h, wpack, eb, cursor + l*NE,
                                                      entryTok, entryW, tmp, l);
        k_combine<<<NTOK/4, 256, 0, stream>>>(tmp, pos01, gamma, beta, h);
    }

    k_pool<<<dim3(BB, 32), 256, 0, stream>>>(h, headW, out_acc);
    k_final<<<1, 64, 0, stream>>>(out_acc, headb, out);
}

// Round 5
// 513.316 us; speedup vs baseline: 2.6131x; 1.1329x over previous
//
#include <hip/hip_runtime.h>
#include <math.h>

#define DIM 240
#define NE 8
#define DEPTH 8
#define BB 8
#define SS 2048
#define NTOK (BB * SS)
#define TWO_PI 6.28318530717958647692f
#define HSTRIDE 241

typedef __attribute__((ext_vector_type(8))) short s16x8;
typedef __attribute__((ext_vector_type(4))) float f32x4;

// ---------------- workspace layout ----------------
#define ALIGN256(x) (((x) + 255) & ~((size_t)255))
static const size_t OFF_COST   = 0;                                        // 240*240 f
static const size_t OFF_SINT   = ALIGN256(OFF_COST  + 240*240*4);          // 240*240 f
static const size_t OFF_H      = ALIGN256(OFF_SINT  + 240*240*4);          // NTOK*DIM bf16
static const size_t OFF_TMP    = ALIGN256(OFF_H     + (size_t)NTOK*DIM*2); // NE*NTOK*DIM f
static const size_t OFF_ENTW   = ALIGN256(OFF_TMP   + (size_t)NE*NTOK*DIM*4); // NE*NTOK f
static const size_t OFF_OUTACC = ALIGN256(OFF_ENTW  + (size_t)NE*NTOK*4);  // 8 f
static const size_t OFF_POS01  = ALIGN256(OFF_OUTACC + 8*4);               // 2*NTOK i
static const size_t OFF_ENTTOK = ALIGN256(OFF_POS01  + 2*NTOK*4);          // NE*NTOK i
static const size_t OFF_CURSOR = ALIGN256(OFF_ENTTOK + (size_t)NE*NTOK*4); // 64 i
// packed bf16 weights: 64 experts x [ks 8][tile 16][lane 64][j 8], tile 15 = zeros
static const size_t WPACK_PER_E = 8 * 16 * 64 * 8;                         // 65536 elems
static const size_t OFF_WPACK  = ALIGN256(OFF_CURSOR + 64*4);

__device__ inline short f2bf(float x) {
    unsigned u = __builtin_bit_cast(unsigned, x);
    u += 0x7fffu + ((u >> 16) & 1u);   // RNE
    return (short)(u >> 16);
}
__device__ inline float bf2f(short s) {
    unsigned u = ((unsigned)(unsigned short)s) << 16;
    return __builtin_bit_cast(float, u);
}

// ---------------- kernels ----------------

__global__ void k_init(int* __restrict__ cursor, float* __restrict__ out_acc) {
    int t = threadIdx.x;
    if (t < DEPTH*NE) cursor[t] = 0;
    if (t < BB) out_acc[t] = 0.f;
}

__global__ void k_tables(const float* __restrict__ roots, const float* __restrict__ projW,
                         float* __restrict__ cosT, float* __restrict__ sinT) {
    int s = blockIdx.x;
    int d = threadIdx.x;
    if (d >= DIM) return;
    int j = d % 80;
    float acc = 0.f;
#pragma unroll
    for (int r = 0; r < 8; ++r) acc += roots[s*8 + r] * projW[r*80 + j];
    cosT[s*DIM + d] = cosf(acc);
    sinT[s*DIM + d] = sinf(acc);
}

__global__ void k_cycle(const float* __restrict__ x, const int* __restrict__ step,
                        const float* __restrict__ cosT, const float* __restrict__ sinT,
                        short* __restrict__ hb) {
    int tok = blockIdx.x;
    int d = threadIdx.x;
    if (d >= DIM) return;
    int s = tok % SS;
    int sm = s % 240;
    float pump = 0.8f * sinf((float)step[0] * 0.006f * TWO_PI);
    const float* xr = x + (size_t)tok * DIM;
    const float* cr = cosT + sm * DIM;
    const float* sr = sinT + sm * DIM;
    int dm1 = (d + DIM - 1) % DIM;
    int dm2 = (d + DIM - 2) % DIM;
    float x1d  = xr[d]   * (cr[d]   + pump);
    float x1m1 = xr[dm1] * (cr[dm1] + pump);
    float x1m2 = xr[dm2] * (cr[dm2] + pump);
    float x2d  = x1m1 * sr[d];
    float x3d  = x1m2 * sr[dm1] * cr[d];
    hb[(size_t)tok*DIM + d] = f2bf((x1d + x2d + x3d) * (1.0f/3.0f));
}

// pack expert weights -> MFMA B-frag layout, 16 N-tiles (tile 15 zero), K pad 256
__global__ __launch_bounds__(64) void k_pack(const float* __restrict__ eW, short* __restrict__ wp) {
    int tile = blockIdx.x;   // 0..15
    int ks   = blockIdx.y;   // 0..7
    int eg   = blockIdx.z;   // 0..63
    int lane = threadIdx.x;
    int f  = tile*16 + (lane & 15);
    int d0 = ks*32 + (lane >> 4)*8;
    const float* W = eW + (size_t)eg*DIM*DIM;
    short v[8];
#pragma unroll
    for (int j = 0; j < 8; ++j) {
        int d = d0 + j;
        v[j] = (d < DIM && f < DIM) ? f2bf(W[(size_t)d*DIM + f]) : (short)0;
    }
    s16x8* dst = (s16x8*)(wp + (((size_t)eg*8 + ks)*16 + tile)*512 + lane*8);
    *dst = *(s16x8*)v;
}

// gate phase shared by k_gate0 / k_combgate: hs = 64 rows (stride HSTRIDE) in LDS
__device__ inline void gate_phase(const float* hs, const float* __restrict__ gW,
                                  const float* __restrict__ gb, int* __restrict__ cursor,
                                  int* __restrict__ entryTok, float* __restrict__ entryW,
                                  int* __restrict__ pos01, int tok0, int tid,
                                  float (*lg)[NE], int* le01, int* lli01,
                                  float (*lw)[2], int* lcnt, int* lbase) {
    if (tid < NE) lcnt[tid] = 0;
    __syncthreads();
#pragma unroll
    for (int i = 0; i < 2; ++i) {
        int tt = tid + 256*i;
        int tl = tt >> 3, e = tt & 7;
        const float* hrow = hs + tl*HSTRIDE;
        float acc = gb[e];
        for (int d = 0; d < DIM; d += 4) {
            acc += hrow[d]   * gW[(d)  *NE + e] + hrow[d+1] * gW[(d+1)*NE + e]
                 + hrow[d+2] * gW[(d+2)*NE + e] + hrow[d+3] * gW[(d+3)*NE + e];
        }
        lg[tl][e] = acc;
    }
    __syncthreads();
    if (tid < 64) {
        int i0 = 0; float v0 = lg[tid][0];
#pragma unroll
        for (int k = 1; k < NE; ++k) { float v = lg[tid][k]; if (v > v0) { v0 = v; i0 = k; } }
        int i1 = -1; float v1 = -1e30f;
#pragma unroll
        for (int k = 0; k < NE; ++k) { float v = lg[tid][k]; if (k != i0 && v > v1) { v1 = v; i1 = k; } }
        float e1 = expf(v1 - v0);
        lw[tid][0] = 1.0f / (1.0f + e1);
        lw[tid][1] = e1 / (1.0f + e1);
        le01[tid] = i0 | (i1 << 8);
        int li0 = atomicAdd(&lcnt[i0], 1);
        int li1 = atomicAdd(&lcnt[i1], 1);
        lli01[tid] = li0 | (li1 << 16);
    }
    __syncthreads();
    if (tid < NE) lbase[tid] = atomicAdd(&cursor[tid], lcnt[tid]);
    __syncthreads();
    if (tid < 64) {
        int token = tok0 + tid;
        int i0 = le01[tid] & 0xff, i1 = le01[tid] >> 8;
        int p0 = i0*NTOK + lbase[i0] + (lli01[tid] & 0xffff);
        int p1 = i1*NTOK + lbase[i1] + (lli01[tid] >> 16);
        entryTok[p0] = token; entryW[p0] = lw[tid][0];
        entryTok[p1] = token; entryW[p1] = lw[tid][1];
        pos01[2*token] = p0; pos01[2*token+1] = p1;
    }
}

// layer-0 gate: stage bf16 h -> fp32 LDS, then gate+scatter
__global__ __launch_bounds__(256) void k_gate0(
        const short* __restrict__ hb, const float* __restrict__ gW,
        const float* __restrict__ gb, int* __restrict__ cursor,
        int* __restrict__ entryTok, float* __restrict__ entryW,
        int* __restrict__ pos01) {
    __shared__ float hs[64*HSTRIDE];
    __shared__ float lg[64][NE];
    __shared__ int   le01[64], lli01[64];
    __shared__ float lw[64][2];
    __shared__ int   lcnt[NE], lbase[NE];
    int tid = threadIdx.x;
    int tok0 = blockIdx.x * 64;
    for (int idx = tid; idx < 64*30; idx += 256) {
        int row = idx / 30, c8 = idx - row*30;
        s16x8 v = *(const s16x8*)(hb + (size_t)(tok0+row)*DIM + c8*8);
#pragma unroll
        for (int i = 0; i < 8; ++i) hs[row*HSTRIDE + c8*8 + i] = bf2f(v[i]);
    }
    __syncthreads();
    gate_phase(hs, gW, gb, cursor, entryTok, entryW, pos01, tok0, tid,
               lg, le01, lli01, lw, lcnt, lbase);
}

// grouped expert GEMM: 64 tokens x 240 outs; 4 waves each own 4 N-tiles x all 64 rows
__global__ __launch_bounds__(256) void k_gemm(
        const short* __restrict__ hb, const short* __restrict__ wp,
        const float* __restrict__ eb, const int* __restrict__ cursor,
        const int* __restrict__ entryTok, const float* __restrict__ entryW,
        float* __restrict__ tmp, int layer) {
    int e = blockIdx.y;
    int cnt = cursor[e];
    int t0 = blockIdx.x * 64;
    if (t0 >= cnt) return;
    int ntok = min(64, cnt - t0);
    size_t base = (size_t)e*NTOK + t0;

    __shared__ short As[64*264];
    __shared__ float sw[64];
    __shared__ int stok[64];
    int tid = threadIdx.x;
    if (tid < 64) {
        if (tid < ntok) { stok[tid] = entryTok[base+tid]; sw[tid] = entryW[base+tid]; }
        else            { stok[tid] = 0;                  sw[tid] = 0.f; }
    }
    __syncthreads();
    for (int idx = tid; idx < 64*30; idx += 256) {
        int row = idx / 30, c8 = idx - row*30;
        *(s16x8*)(As + row*264 + c8*8) = *(const s16x8*)(hb + (size_t)stok[row]*DIM + c8*8);
    }
    if (tid < 128) {   // zero K-pad cols 240..255
        int row = tid >> 1, c = 240 + (tid & 1)*8;
        short z[8] = {0,0,0,0,0,0,0,0};
        *(s16x8*)(As + row*264 + c) = *(s16x8*)z;
    }
    __syncthreads();

    int wave = tid >> 6, lane = tid & 63;
    f32x4 acc[4][4];   // [mtile][ntile]
#pragma unroll
    for (int m = 0; m < 4; ++m)
#pragma unroll
        for (int n = 0; n < 4; ++n) acc[m][n] = (f32x4){0.f,0.f,0.f,0.f};

    const short* ab = As + (lane & 15)*264 + (lane >> 4)*8;
    const short* wb = wp + (size_t)(layer*NE + e)*WPACK_PER_E + (size_t)wave*4*512 + lane*8;

    for (int ks = 0; ks < 8; ++ks) {
        s16x8 a0 = *(const s16x8*)(ab + ks*32 + 0*16*264);
        s16x8 a1 = *(const s16x8*)(ab + ks*32 + 1*16*264);
        s16x8 a2 = *(const s16x8*)(ab + ks*32 + 2*16*264);
        s16x8 a3 = *(const s16x8*)(ab + ks*32 + 3*16*264);
#pragma unroll
        for (int n = 0; n < 4; ++n) {
            s16x8 bf = *(const s16x8*)(wb + ((size_t)ks*16 + n)*512);
            acc[0][n] = __builtin_amdgcn_mfma_f32_16x16x32_bf16(a0, bf, acc[0][n], 0, 0, 0);
            acc[1][n] = __builtin_amdgcn_mfma_f32_16x16x32_bf16(a1, bf, acc[1][n], 0, 0, 0);
            acc[2][n] = __builtin_amdgcn_mfma_f32_16x16x32_bf16(a2, bf, acc[2][n], 0, 0, 0);
            acc[3][n] = __builtin_amdgcn_mfma_f32_16x16x32_bf16(a3, bf, acc[3][n], 0, 0, 0);
        }
    }

    const float* ebp = eb + (size_t)(layer*NE + e)*DIM;
    int mrb = (lane >> 4)*4;
#pragma unroll
    for (int n = 0; n < 4; ++n) {
        int col = (wave*4 + n)*16 + (lane & 15);
        if (col < DIM) {
            float bias = ebp[col];
#pragma unroll
            for (int m = 0; m < 4; ++m) {
#pragma unroll
                for (int r = 0; r < 4; ++r) {
                    int row = m*16 + mrb + r;
                    if (row < ntok)
                        tmp[(base + row)*DIM + col] = (acc[m][n][r] + bias) * sw[row];
                }
            }
        }
    }
}

// fused: combine(tmp)->LN->h (bf16 + fp32 LDS), then gate+scatter for next layer
__global__ __launch_bounds__(256) void k_combgate(
        const float* __restrict__ tmp, int* __restrict__ pos01,
        const float* __restrict__ gamma, const float* __restrict__ beta,
        short* __restrict__ hb, const float* __restrict__ gW,
        const float* __restrict__ gb, int* __restrict__ cursor,
        int* __restrict__ entryTok, float* __restrict__ entryW, int do_gate) {
    __shared__ float hs[64*HSTRIDE];
    __shared__ float lg[64][NE];
    __shared__ int   le01[64], lli01[64];
    __shared__ float lw[64][2];
    __shared__ int   lcnt[NE], lbase[NE];
    int tid = threadIdx.x;
    int wave = tid >> 6, lane = tid & 63;
    int tok0 = blockIdx.x * 64;

    float gg[4], bb[4];
#pragma unroll
    for (int j = 0; j < 4; ++j) {
        int d = lane + 64*j;
        gg[j] = (d < DIM) ? gamma[d] : 0.f;
        bb[j] = (d < DIM) ? beta[d]  : 0.f;
    }

    for (int jt = 0; jt < 16; ++jt) {
        int lt = wave*16 + jt;
        int token = tok0 + lt;
        int p0 = pos01[2*token], p1 = pos01[2*token+1];
        const float* a = tmp + (size_t)p0*DIM;
        const float* b = tmp + (size_t)p1*DIM;
        float v[4]; float sum = 0.f;
#pragma unroll
        for (int j = 0; j < 4; ++j) {
            int d = lane + 64*j;
            float y = (d < DIM) ? (a[d] + b[d]) : 0.f;
            v[j] = y; sum += y;
        }
#pragma unroll
        for (int o = 32; o > 0; o >>= 1) sum += __shfl_xor(sum, o, 64);
        float mean = sum * (1.0f/DIM);
        float vs = 0.f;
#pragma unroll
        for (int j = 0; j < 4; ++j) {
            int d = lane + 64*j;
            if (d < DIM) { float t = v[j] - mean; vs += t*t; }
        }
#pragma unroll
        for (int o = 32; o > 0; o >>= 1) vs += __shfl_xor(vs, o, 64);
        float rs = rsqrtf(vs * (1.0f/DIM) + 1e-5f);
#pragma unroll
        for (int j = 0; j < 4; ++j) {
            int d = lane + 64*j;
            if (d < DIM) {
                float hn = v[j] + (v[j] - mean) * rs * gg[j] + bb[j];
                hs[lt*HSTRIDE + d] = hn;
                hb[(size_t)token*DIM + d] = f2bf(hn);
            }
        }
    }
    __syncthreads();
    if (!do_gate) return;
    gate_phase(hs, gW, gb, cursor, entryTok, entryW, pos01, tok0, tid,
               lg, le01, lli01, lw, lcnt, lbase);
}

__global__ void k_pool(const short* __restrict__ hb, const float* __restrict__ headW,
                       float* __restrict__ out_acc) {
    int b = blockIdx.x, chunk = blockIdx.y;
    int tid = threadIdx.x;
    float acc = 0.f;
    if (tid < DIM) {
        float hw = headW[tid];
        for (int s = 0; s < 64; ++s) {
            int tok = b*SS + chunk*64 + s;
            acc += bf2f(hb[(size_t)tok*DIM + tid]) * hw;
        }
    }
    __shared__ float red[256];
    red[tid] = acc;
    __syncthreads();
    for (int o = 128; o > 0; o >>= 1) { if (tid < o) red[tid] += red[tid+o]; __syncthreads(); }
    if (tid == 0) atomicAdd(&out_acc[b], red[0]);
}

__global__ void k_final(const float* __restrict__ out_acc, const float* __restrict__ headb,
                        float* __restrict__ out) {
    int b = threadIdx.x;
    if (b < BB) {
        float z = out_acc[b] * (1.0f/SS) + headb[0];
        out[b] = 1.0f / (1.0f + expf(-z));
    }
}

// ---------------- launch ----------------
extern "C" void kernel_launch(void* const* d_in, const int* in_sizes, int n_in,
                              void* d_out, int out_size, void* d_ws, size_t ws_size,
                              hipStream_t stream) {
    const float* x     = (const float*)d_in[0];
    const int*   step  = (const int*)  d_in[1];
    const float* roots = (const float*)d_in[2];
    const float* projW = (const float*)d_in[3];
    const float* gateW = (const float*)d_in[4];
    const float* gateb = (const float*)d_in[5];
    const float* eW    = (const float*)d_in[6];
    const float* eb    = (const float*)d_in[7];
    const float* gamma = (const float*)d_in[8];
    const float* beta  = (const float*)d_in[9];
    const float* headW = (const float*)d_in[10];
    const float* headb = (const float*)d_in[11];
    float* out = (float*)d_out;

    char* w = (char*)d_ws;
    float* cosT    = (float*)(w + OFF_COST);
    float* sinT    = (float*)(w + OFF_SINT);
    short* hb      = (short*)(w + OFF_H);
    float* tmp     = (float*)(w + OFF_TMP);
    float* entryW  = (float*)(w + OFF_ENTW);
    float* out_acc = (float*)(w + OFF_OUTACC);
    int*   pos01   = (int*)  (w + OFF_POS01);
    int*   entryTok= (int*)  (w + OFF_ENTTOK);
    int*   cursor  = (int*)  (w + OFF_CURSOR);
    short* wpack   = (short*)(w + OFF_WPACK);

    k_init<<<1, 128, 0, stream>>>(cursor, out_acc);
    k_tables<<<240, 256, 0, stream>>>(roots, projW, cosT, sinT);
    k_pack<<<dim3(16, 8, 64), 64, 0, stream>>>(eW, wpack);
    k_cycle<<<NTOK, 256, 0, stream>>>(x, step, cosT, sinT, hb);
    k_gate0<<<NTOK/64, 256, 0, stream>>>(hb, gateW, gateb, cursor,
                                         entryTok, entryW, pos01);

    for (int l = 0; l < DEPTH; ++l) {
        k_gemm<<<dim3(NTOK/64, NE), 256, 0, stream>>>(hb, wpack, eb, cursor + l*NE,
                                                      entryTok, entryW, tmp, l);
        int nl = (l < DEPTH-1) ? l+1 : l;   // gW/gb/cursor for next layer (unused when !do_gate)
        k_combgate<<<NTOK/64, 256, 0, stream>>>(tmp, pos01, gamma, beta, hb,
                                                gateW + (size_t)nl*DIM*NE, gateb + nl*NE,
                                                cursor + nl*NE, entryTok, entryW,
                                                (l < DEPTH-1) ? 1 : 0);
    }

    k_pool<<<dim3(BB, 32), 256, 0, stream>>>(hb, headW, out_acc);
    k_final<<<1, 64, 0, stream>>>(out_acc, headb, out);
}

// Round 6
// 505.614 us; speedup vs baseline: 2.6529x; 1.0152x over previous
//
#include <hip/hip_runtime.h>
#include <math.h>

#define DIM 240
#define NE 8
#define DEPTH 8
#define BB 8
#define SS 2048
#define NTOK (BB * SS)
#define TWO_PI 6.28318530717958647692f
#define HSTRIDE 241

typedef __attribute__((ext_vector_type(8))) short s16x8;
typedef __attribute__((ext_vector_type(4))) float f32x4;

// ---------------- workspace layout ----------------
#define ALIGN256(x) (((x) + 255) & ~((size_t)255))
static const size_t OFF_COST   = 0;                                        // 240*240 f
static const size_t OFF_SINT   = ALIGN256(OFF_COST  + 240*240*4);          // 240*240 f
static const size_t OFF_H      = ALIGN256(OFF_SINT  + 240*240*4);          // NTOK*DIM bf16
static const size_t OFF_TMP    = ALIGN256(OFF_H     + (size_t)NTOK*DIM*2); // NE*NTOK*DIM bf16
static const size_t OFF_ENTW   = ALIGN256(OFF_TMP   + (size_t)NE*NTOK*DIM*2); // NE*NTOK f
static const size_t OFF_OUTACC = ALIGN256(OFF_ENTW  + (size_t)NE*NTOK*4);  // 8 f
static const size_t OFF_POS01  = ALIGN256(OFF_OUTACC + 8*4);               // 2*NTOK i
static const size_t OFF_ENTTOK = ALIGN256(OFF_POS01  + 2*NTOK*4);          // NE*NTOK i
static const size_t OFF_CURSOR = ALIGN256(OFF_ENTTOK + (size_t)NE*NTOK*4); // 64 i
// packed bf16 weights: 64 experts x [ks 8][tile 16][lane 64][j 8], tile 15 = zeros
static const size_t WPACK_PER_E = 8 * 16 * 64 * 8;                         // 65536 elems
static const size_t OFF_WPACK  = ALIGN256(OFF_CURSOR + 64*4);

__device__ inline short f2bf(float x) {
    unsigned u = __builtin_bit_cast(unsigned, x);
    u += 0x7fffu + ((u >> 16) & 1u);   // RNE
    return (short)(u >> 16);
}
__device__ inline float bf2f(short s) {
    unsigned u = ((unsigned)(unsigned short)s) << 16;
    return __builtin_bit_cast(float, u);
}

// ---------------- kernels ----------------

// blocks 0..239: cos/sin tables; block 240: zero cursor/out_acc
__global__ void k_tables(const float* __restrict__ roots, const float* __restrict__ projW,
                         float* __restrict__ cosT, float* __restrict__ sinT,
                         int* __restrict__ cursor, float* __restrict__ out_acc) {
    int s = blockIdx.x;
    int d = threadIdx.x;
    if (s == 240) {
        if (d < DEPTH*NE) cursor[d] = 0;
        if (d < BB) out_acc[d] = 0.f;
        return;
    }
    if (d >= DIM) return;
    int j = d % 80;
    float acc = 0.f;
#pragma unroll
    for (int r = 0; r < 8; ++r) acc += roots[s*8 + r] * projW[r*80 + j];
    cosT[s*DIM + d] = cosf(acc);
    sinT[s*DIM + d] = sinf(acc);
}

__global__ void k_cycle(const float* __restrict__ x, const int* __restrict__ step,
                        const float* __restrict__ cosT, const float* __restrict__ sinT,
                        short* __restrict__ hb) {
    int tok = blockIdx.x;
    int d = threadIdx.x;
    if (d >= DIM) return;
    int s = tok % SS;
    int sm = s % 240;
    float pump = 0.8f * sinf((float)step[0] * 0.006f * TWO_PI);
    const float* xr = x + (size_t)tok * DIM;
    const float* cr = cosT + sm * DIM;
    const float* sr = sinT + sm * DIM;
    int dm1 = (d + DIM - 1) % DIM;
    int dm2 = (d + DIM - 2) % DIM;
    float x1d  = xr[d]   * (cr[d]   + pump);
    float x1m1 = xr[dm1] * (cr[dm1] + pump);
    float x1m2 = xr[dm2] * (cr[dm2] + pump);
    float x2d  = x1m1 * sr[d];
    float x3d  = x1m2 * sr[dm1] * cr[d];
    hb[(size_t)tok*DIM + d] = f2bf((x1d + x2d + x3d) * (1.0f/3.0f));
}

// pack expert weights -> MFMA B-frag layout, 16 N-tiles (tile 15 zero), K pad 256
__global__ __launch_bounds__(64) void k_pack(const float* __restrict__ eW, short* __restrict__ wp) {
    int tile = blockIdx.x;   // 0..15
    int ks   = blockIdx.y;   // 0..7
    int eg   = blockIdx.z;   // 0..63
    int lane = threadIdx.x;
    int f  = tile*16 + (lane & 15);
    int d0 = ks*32 + (lane >> 4)*8;
    const float* W = eW + (size_t)eg*DIM*DIM;
    short v[8];
#pragma unroll
    for (int j = 0; j < 8; ++j) {
        int d = d0 + j;
        v[j] = (d < DIM && f < DIM) ? f2bf(W[(size_t)d*DIM + f]) : (short)0;
    }
    s16x8* dst = (s16x8*)(wp + (((size_t)eg*8 + ks)*16 + tile)*512 + lane*8);
    *dst = *(s16x8*)v;
}

// gate phase shared by k_gate0 / k_combgate: hs = 64 rows (stride HSTRIDE) in LDS
__device__ inline void gate_phase(const float* hs, const float* __restrict__ gW,
                                  const float* __restrict__ gb, int* __restrict__ cursor,
                                  int* __restrict__ entryTok, float* __restrict__ entryW,
                                  int* __restrict__ pos01, int tok0, int tid,
                                  float* gWs, float (*lg)[NE], int* le01, int* lli01,
                                  float (*lw)[2], int* lcnt, int* lbase) {
    if (tid < NE) lcnt[tid] = 0;
    for (int idx = tid; idx < DIM*NE; idx += 256) gWs[idx] = gW[idx];
    __syncthreads();
#pragma unroll
    for (int i = 0; i < 2; ++i) {
        int tt = tid + 256*i;
        int tl = tt >> 3, e = tt & 7;
        const float* hrow = hs + tl*HSTRIDE;
        float acc = gb[e];
        for (int d = 0; d < DIM; d += 4) {
            acc += hrow[d]   * gWs[(d)  *NE + e] + hrow[d+1] * gWs[(d+1)*NE + e]
                 + hrow[d+2] * gWs[(d+2)*NE + e] + hrow[d+3] * gWs[(d+3)*NE + e];
        }
        lg[tl][e] = acc;
    }
    __syncthreads();
    if (tid < 64) {
        int i0 = 0; float v0 = lg[tid][0];
#pragma unroll
        for (int k = 1; k < NE; ++k) { float v = lg[tid][k]; if (v > v0) { v0 = v; i0 = k; } }
        int i1 = -1; float v1 = -1e30f;
#pragma unroll
        for (int k = 0; k < NE; ++k) { float v = lg[tid][k]; if (k != i0 && v > v1) { v1 = v; i1 = k; } }
        float e1 = expf(v1 - v0);
        lw[tid][0] = 1.0f / (1.0f + e1);
        lw[tid][1] = e1 / (1.0f + e1);
        le01[tid] = i0 | (i1 << 8);
        int li0 = atomicAdd(&lcnt[i0], 1);
        int li1 = atomicAdd(&lcnt[i1], 1);
        lli01[tid] = li0 | (li1 << 16);
    }
    __syncthreads();
    if (tid < NE) lbase[tid] = atomicAdd(&cursor[tid], lcnt[tid]);
    __syncthreads();
    if (tid < 64) {
        int token = tok0 + tid;
        int i0 = le01[tid] & 0xff, i1 = le01[tid] >> 8;
        int p0 = i0*NTOK + lbase[i0] + (lli01[tid] & 0xffff);
        int p1 = i1*NTOK + lbase[i1] + (lli01[tid] >> 16);
        entryTok[p0] = token; entryW[p0] = lw[tid][0];
        entryTok[p1] = token; entryW[p1] = lw[tid][1];
        pos01[2*token] = p0; pos01[2*token+1] = p1;
    }
}

// layer-0 gate: stage bf16 h -> fp32 LDS, then gate+scatter
__global__ __launch_bounds__(256) void k_gate0(
        const short* __restrict__ hb, const float* __restrict__ gW,
        const float* __restrict__ gb, int* __restrict__ cursor,
        int* __restrict__ entryTok, float* __restrict__ entryW,
        int* __restrict__ pos01) {
    __shared__ float hs[64*HSTRIDE];
    __shared__ float gWs[DIM*NE];
    __shared__ float lg[64][NE];
    __shared__ int   le01[64], lli01[64];
    __shared__ float lw[64][2];
    __shared__ int   lcnt[NE], lbase[NE];
    int tid = threadIdx.x;
    int tok0 = blockIdx.x * 64;
    for (int idx = tid; idx < 64*30; idx += 256) {
        int row = idx / 30, c8 = idx - row*30;
        s16x8 v = *(const s16x8*)(hb + (size_t)(tok0+row)*DIM + c8*8);
#pragma unroll
        for (int i = 0; i < 8; ++i) hs[row*HSTRIDE + c8*8 + i] = bf2f(v[i]);
    }
    gate_phase(hs, gW, gb, cursor, entryTok, entryW, pos01, tok0, tid,
               gWs, lg, le01, lli01, lw, lcnt, lbase);
}

// grouped expert GEMM: 64 tokens x 240 outs; 4 waves each own 4 N-tiles x all 64 rows
__global__ __launch_bounds__(256) void k_gemm(
        const short* __restrict__ hb, const short* __restrict__ wp,
        const float* __restrict__ eb, const int* __restrict__ cursor,
        const int* __restrict__ entryTok, const float* __restrict__ entryW,
        short* __restrict__ tmp, int layer) {
    int e = blockIdx.y;
    int cnt = cursor[e];
    int t0 = blockIdx.x * 64;
    if (t0 >= cnt) return;
    int ntok = min(64, cnt - t0);
    size_t base = (size_t)e*NTOK + t0;

    __shared__ short As[64*264];
    __shared__ float sw[64];
    __shared__ int stok[64];
    int tid = threadIdx.x;
    if (tid < 64) {
        if (tid < ntok) { stok[tid] = entryTok[base+tid]; sw[tid] = entryW[base+tid]; }
        else            { stok[tid] = 0;                  sw[tid] = 0.f; }
    }
    __syncthreads();
    for (int idx = tid; idx < 64*30; idx += 256) {
        int row = idx / 30, c8 = idx - row*30;
        *(s16x8*)(As + row*264 + c8*8) = *(const s16x8*)(hb + (size_t)stok[row]*DIM + c8*8);
    }
    if (tid < 128) {   // zero K-pad cols 240..255
        int row = tid >> 1, c = 240 + (tid & 1)*8;
        short z[8] = {0,0,0,0,0,0,0,0};
        *(s16x8*)(As + row*264 + c) = *(s16x8*)z;
    }
    __syncthreads();

    int wave = tid >> 6, lane = tid & 63;
    f32x4 acc[4][4];   // [mtile][ntile]
#pragma unroll
    for (int m = 0; m < 4; ++m)
#pragma unroll
        for (int n = 0; n < 4; ++n) acc[m][n] = (f32x4){0.f,0.f,0.f,0.f};

    const short* ab = As + (lane & 15)*264 + (lane >> 4)*8;
    const short* wb = wp + (size_t)(layer*NE + e)*WPACK_PER_E + (size_t)wave*4*512 + lane*8;

    for (int ks = 0; ks < 8; ++ks) {
        s16x8 a0 = *(const s16x8*)(ab + ks*32 + 0*16*264);
        s16x8 a1 = *(const s16x8*)(ab + ks*32 + 1*16*264);
        s16x8 a2 = *(const s16x8*)(ab + ks*32 + 2*16*264);
        s16x8 a3 = *(const s16x8*)(ab + ks*32 + 3*16*264);
#pragma unroll
        for (int n = 0; n < 4; ++n) {
            s16x8 bf = *(const s16x8*)(wb + ((size_t)ks*16 + n)*512);
            acc[0][n] = __builtin_amdgcn_mfma_f32_16x16x32_bf16(a0, bf, acc[0][n], 0, 0, 0);
            acc[1][n] = __builtin_amdgcn_mfma_f32_16x16x32_bf16(a1, bf, acc[1][n], 0, 0, 0);
            acc[2][n] = __builtin_amdgcn_mfma_f32_16x16x32_bf16(a2, bf, acc[2][n], 0, 0, 0);
            acc[3][n] = __builtin_amdgcn_mfma_f32_16x16x32_bf16(a3, bf, acc[3][n], 0, 0, 0);
        }
    }

    const float* ebp = eb + (size_t)(layer*NE + e)*DIM;
    int mrb = (lane >> 4)*4;
#pragma unroll
    for (int n = 0; n < 4; ++n) {
        int col = (wave*4 + n)*16 + (lane & 15);
        if (col < DIM) {
            float bias = ebp[col];
#pragma unroll
            for (int m = 0; m < 4; ++m) {
#pragma unroll
                for (int r = 0; r < 4; ++r) {
                    int row = m*16 + mrb + r;
                    if (row < ntok)
                        tmp[(base + row)*DIM + col] = f2bf((acc[m][n][r] + bias) * sw[row]);
                }
            }
        }
    }
}

// fused: combine(tmp bf16)->LN->h (bf16 + fp32 LDS), then gate+scatter for next layer
__global__ __launch_bounds__(256) void k_combgate(
        const short* __restrict__ tmp, int* __restrict__ pos01,
        const float* __restrict__ gamma, const float* __restrict__ beta,
        short* __restrict__ hb, const float* __restrict__ gW,
        const float* __restrict__ gb, int* __restrict__ cursor,
        int* __restrict__ entryTok, float* __restrict__ entryW, int do_gate) {
    __shared__ float hs[64*HSTRIDE];
    __shared__ float gWs[DIM*NE];
    __shared__ float lg[64][NE];
    __shared__ int   le01[64], lli01[64];
    __shared__ float lw[64][2];
    __shared__ int   lcnt[NE], lbase[NE];
    int tid = threadIdx.x;
    int wave = tid >> 6, lane = tid & 63;
    int tok0 = blockIdx.x * 64;

    float gg[4], bb[4];
#pragma unroll
    for (int j = 0; j < 4; ++j) {
        int d = lane + 64*j;
        gg[j] = (d < DIM) ? gamma[d] : 0.f;
        bb[j] = (d < DIM) ? beta[d]  : 0.f;
    }

    for (int jt = 0; jt < 16; ++jt) {
        int lt = wave*16 + jt;
        int token = tok0 + lt;
        int p0 = pos01[2*token], p1 = pos01[2*token+1];
        const short* a = tmp + (size_t)p0*DIM;
        const short* b = tmp + (size_t)p1*DIM;
        float v[4]; float sum = 0.f;
#pragma unroll
        for (int j = 0; j < 4; ++j) {
            int d = lane + 64*j;
            float y = (d < DIM) ? (bf2f(a[d]) + bf2f(b[d])) : 0.f;
            v[j] = y; sum += y;
        }
#pragma unroll
        for (int o = 32; o > 0; o >>= 1) sum += __shfl_xor(sum, o, 64);
        float mean = sum * (1.0f/DIM);
        float vs = 0.f;
#pragma unroll
        for (int j = 0; j < 4; ++j) {
            int d = lane + 64*j;
            if (d < DIM) { float t = v[j] - mean; vs += t*t; }
        }
#pragma unroll
        for (int o = 32; o > 0; o >>= 1) vs += __shfl_xor(vs, o, 64);
        float rs = rsqrtf(vs * (1.0f/DIM) + 1e-5f);
#pragma unroll
        for (int j = 0; j < 4; ++j) {
            int d = lane + 64*j;
            if (d < DIM) {
                float hn = v[j] + (v[j] - mean) * rs * gg[j] + bb[j];
                hs[lt*HSTRIDE + d] = hn;
                hb[(size_t)token*DIM + d] = f2bf(hn);
            }
        }
    }
    __syncthreads();
    if (!do_gate) return;
    gate_phase(hs, gW, gb, cursor, entryTok, entryW, pos01, tok0, tid,
               gWs, lg, le01, lli01, lw, lcnt, lbase);
}

__global__ void k_pool(const short* __restrict__ hb, const float* __restrict__ headW,
                       float* __restrict__ out_acc) {
    int b = blockIdx.x, chunk = blockIdx.y;
    int tid = threadIdx.x;
    float acc = 0.f;
    if (tid < DIM) {
        float hw = headW[tid];
        for (int s = 0; s < 64; ++s) {
            int tok = b*SS + chunk*64 + s;
            acc += bf2f(hb[(size_t)tok*DIM + tid]) * hw;
        }
    }
    __shared__ float red[256];
    red[tid] = acc;
    __syncthreads();
    for (int o = 128; o > 0; o >>= 1) { if (tid < o) red[tid] += red[tid+o]; __syncthreads(); }
    if (tid == 0) atomicAdd(&out_acc[b], red[0]);
}

__global__ void k_final(const float* __restrict__ out_acc, const float* __restrict__ headb,
                        float* __restrict__ out) {
    int b = threadIdx.x;
    if (b < BB) {
        float z = out_acc[b] * (1.0f/SS) + headb[0];
        out[b] = 1.0f / (1.0f + expf(-z));
    }
}

// ---------------- launch ----------------
extern "C" void kernel_launch(void* const* d_in, const int* in_sizes, int n_in,
                              void* d_out, int out_size, void* d_ws, size_t ws_size,
                              hipStream_t stream) {
    const float* x     = (const float*)d_in[0];
    const int*   step  = (const int*)  d_in[1];
    const float* roots = (const float*)d_in[2];
    const float* projW = (const float*)d_in[3];
    const float* gateW = (const float*)d_in[4];
    const float* gateb = (const float*)d_in[5];
    const float* eW    = (const float*)d_in[6];
    const float* eb    = (const float*)d_in[7];
    const float* gamma = (const float*)d_in[8];
    const float* beta  = (const float*)d_in[9];
    const float* headW = (const float*)d_in[10];
    const float* headb = (const float*)d_in[11];
    float* out = (float*)d_out;

    char* w = (char*)d_ws;
    float* cosT    = (float*)(w + OFF_COST);
    float* sinT    = (float*)(w + OFF_SINT);
    short* hb      = (short*)(w + OFF_H);
    short* tmp     = (short*)(w + OFF_TMP);
    float* entryW  = (float*)(w + OFF_ENTW);
    float* out_acc = (float*)(w + OFF_OUTACC);
    int*   pos01   = (int*)  (w + OFF_POS01);
    int*   entryTok= (int*)  (w + OFF_ENTTOK);
    int*   cursor  = (int*)  (w + OFF_CURSOR);
    short* wpack   = (short*)(w + OFF_WPACK);

    k_tables<<<241, 256, 0, stream>>>(roots, projW, cosT, sinT, cursor, out_acc);
    k_pack<<<dim3(16, 8, 64), 64, 0, stream>>>(eW, wpack);
    k_cycle<<<NTOK, 256, 0, stream>>>(x, step, cosT, sinT, hb);
    k_gate0<<<NTOK/64, 256, 0, stream>>>(hb, gateW, gateb, cursor,
                                         entryTok, entryW, pos01);

    for (int l = 0; l < DEPTH; ++l) {
        k_gemm<<<dim3(NTOK/64, NE), 256, 0, stream>>>(hb, wpack, eb, cursor + l*NE,
                                                      entryTok, entryW, tmp, l);
        int nl = (l < DEPTH-1) ? l+1 : l;
        k_combgate<<<NTOK/64, 256, 0, stream>>>(tmp, pos01, gamma, beta, hb,
                                                gateW + (size_t)nl*DIM*NE, gateb + nl*NE,
                                                cursor + nl*NE, entryTok, entryW,
                                                (l < DEPTH-1) ? 1 : 0);
    }

    k_pool<<<dim3(BB, 32), 256, 0, stream>>>(hb, headW, out_acc);
    k_final<<<1, 64, 0, stream>>>(out_acc, headb, out);
}

// Round 7
// 466.385 us; speedup vs baseline: 2.8761x; 1.0841x over previous
//
#include <hip/hip_runtime.h>
#include <math.h>

#define DIM 240
#define NE 8
#define DEPTH 8
#define BB 8
#define SS 2048
#define NTOK (BB * SS)
#define TWO_PI 6.28318530717958647692f
#define HSTRIDE 241
#define GTOK 32   // tokens per gate/combine block

typedef __attribute__((ext_vector_type(8))) short s16x8;
typedef __attribute__((ext_vector_type(4))) float f32x4;

// ---------------- workspace layout ----------------
#define ALIGN256(x) (((x) + 255) & ~((size_t)255))
static const size_t OFF_COST   = 0;                                        // 240*240 f
static const size_t OFF_SINT   = ALIGN256(OFF_COST  + 240*240*4);          // 240*240 f
static const size_t OFF_H      = ALIGN256(OFF_SINT  + 240*240*4);          // NTOK*DIM bf16
static const size_t OFF_TMP    = ALIGN256(OFF_H     + (size_t)NTOK*DIM*2); // NE*NTOK*DIM bf16
static const size_t OFF_ENTW   = ALIGN256(OFF_TMP   + (size_t)NE*NTOK*DIM*2); // NE*NTOK f
static const size_t OFF_OUTACC = ALIGN256(OFF_ENTW  + (size_t)NE*NTOK*4);  // 8 f
static const size_t OFF_POS01  = ALIGN256(OFF_OUTACC + 8*4);               // 2*NTOK i
static const size_t OFF_ENTTOK = ALIGN256(OFF_POS01  + 2*NTOK*4);          // NE*NTOK i
static const size_t OFF_CURSOR = ALIGN256(OFF_ENTTOK + (size_t)NE*NTOK*4); // 64 i
static const size_t WPACK_PER_E = 8 * 16 * 64 * 8;                         // 65536 elems
static const size_t OFF_WPACK  = ALIGN256(OFF_CURSOR + 64*4);

__device__ inline short f2bf(float x) {
    unsigned u = __builtin_bit_cast(unsigned, x);
    u += 0x7fffu + ((u >> 16) & 1u);   // RNE
    return (short)(u >> 16);
}
__device__ inline float bf2f(short s) {
    unsigned u = ((unsigned)(unsigned short)s) << 16;
    return __builtin_bit_cast(float, u);
}

// ---------------- kernels ----------------

// blocks 0..239: cos/sin tables; block 240: zero cursor/out_acc
__global__ void k_tables(const float* __restrict__ roots, const float* __restrict__ projW,
                         float* __restrict__ cosT, float* __restrict__ sinT,
                         int* __restrict__ cursor, float* __restrict__ out_acc) {
    int s = blockIdx.x;
    int d = threadIdx.x;
    if (s == 240) {
        if (d < DEPTH*NE) cursor[d] = 0;
        if (d < BB) out_acc[d] = 0.f;
        return;
    }
    if (d >= DIM) return;
    int j = d % 80;
    float acc = 0.f;
#pragma unroll
    for (int r = 0; r < 8; ++r) acc += roots[s*8 + r] * projW[r*80 + j];
    cosT[s*DIM + d] = cosf(acc);
    sinT[s*DIM + d] = sinf(acc);
}

__global__ void k_cycle(const float* __restrict__ x, const int* __restrict__ step,
                        const float* __restrict__ cosT, const float* __restrict__ sinT,
                        short* __restrict__ hb) {
    int tok = blockIdx.x;
    int d = threadIdx.x;
    if (d >= DIM) return;
    int s = tok % SS;
    int sm = s % 240;
    float pump = 0.8f * sinf((float)step[0] * 0.006f * TWO_PI);
    const float* xr = x + (size_t)tok * DIM;
    const float* cr = cosT + sm * DIM;
    const float* sr = sinT + sm * DIM;
    int dm1 = (d + DIM - 1) % DIM;
    int dm2 = (d + DIM - 2) % DIM;
    float x1d  = xr[d]   * (cr[d]   + pump);
    float x1m1 = xr[dm1] * (cr[dm1] + pump);
    float x1m2 = xr[dm2] * (cr[dm2] + pump);
    float x2d  = x1m1 * sr[d];
    float x3d  = x1m2 * sr[dm1] * cr[d];
    hb[(size_t)tok*DIM + d] = f2bf((x1d + x2d + x3d) * (1.0f/3.0f));
}

// pack expert weights -> MFMA B-frag layout, 16 N-tiles (tile 15 zero), K pad 256
__global__ __launch_bounds__(64) void k_pack(const float* __restrict__ eW, short* __restrict__ wp) {
    int tile = blockIdx.x;   // 0..15
    int ks   = blockIdx.y;   // 0..7
    int eg   = blockIdx.z;   // 0..63
    int lane = threadIdx.x;
    int f  = tile*16 + (lane & 15);
    int d0 = ks*32 + (lane >> 4)*8;
    const float* W = eW + (size_t)eg*DIM*DIM;
    short v[8];
#pragma unroll
    for (int j = 0; j < 8; ++j) {
        int d = d0 + j;
        v[j] = (d < DIM && f < DIM) ? f2bf(W[(size_t)d*DIM + f]) : (short)0;
    }
    s16x8* dst = (s16x8*)(wp + (((size_t)eg*8 + ks)*16 + tile)*512 + lane*8);
    *dst = *(s16x8*)v;
}

// gate phase for GTOK=32 rows in LDS (fp32, stride HSTRIDE); 256 threads = 32 tok x 8 exp
__device__ inline void gate_phase(const float* hs, const float* __restrict__ gW,
                                  const float* __restrict__ gb, int* __restrict__ cursor,
                                  int* __restrict__ entryTok, float* __restrict__ entryW,
                                  int* __restrict__ pos01, int tok0, int tid,
                                  float* gWs, float (*lg)[NE], int* le01, int* lli01,
                                  float (*lw)[2], int* lcnt, int* lbase) {
    if (tid < NE) lcnt[tid] = 0;
    for (int idx = tid; idx < DIM*NE; idx += 256) gWs[idx] = gW[idx];
    __syncthreads();
    {
        int tl = tid >> 3, e = tid & 7;
        const float* hrow = hs + tl*HSTRIDE;
        float acc = gb[e];
        for (int d = 0; d < DIM; d += 4) {
            acc += hrow[d]   * gWs[(d)  *NE + e] + hrow[d+1] * gWs[(d+1)*NE + e]
                 + hrow[d+2] * gWs[(d+2)*NE + e] + hrow[d+3] * gWs[(d+3)*NE + e];
        }
        lg[tl][e] = acc;
    }
    __syncthreads();
    if (tid < GTOK) {
        int i0 = 0; float v0 = lg[tid][0];
#pragma unroll
        for (int k = 1; k < NE; ++k) { float v = lg[tid][k]; if (v > v0) { v0 = v; i0 = k; } }
        int i1 = -1; float v1 = -1e30f;
#pragma unroll
        for (int k = 0; k < NE; ++k) { float v = lg[tid][k]; if (k != i0 && v > v1) { v1 = v; i1 = k; } }
        float e1 = expf(v1 - v0);
        lw[tid][0] = 1.0f / (1.0f + e1);
        lw[tid][1] = e1 / (1.0f + e1);
        le01[tid] = i0 | (i1 << 8);
        int li0 = atomicAdd(&lcnt[i0], 1);
        int li1 = atomicAdd(&lcnt[i1], 1);
        lli01[tid] = li0 | (li1 << 16);
    }
    __syncthreads();
    if (tid < NE) lbase[tid] = atomicAdd(&cursor[tid], lcnt[tid]);
    __syncthreads();
    if (tid < GTOK) {
        int token = tok0 + tid;
        int i0 = le01[tid] & 0xff, i1 = le01[tid] >> 8;
        int p0 = i0*NTOK + lbase[i0] + (lli01[tid] & 0xffff);
        int p1 = i1*NTOK + lbase[i1] + (lli01[tid] >> 16);
        entryTok[p0] = token; entryW[p0] = lw[tid][0];
        entryTok[p1] = token; entryW[p1] = lw[tid][1];
        pos01[2*token] = p0; pos01[2*token+1] = p1;
    }
}

// layer-0 gate: stage bf16 h -> fp32 LDS (32 rows), then gate+scatter
__global__ __launch_bounds__(256) void k_gate0(
        const short* __restrict__ hb, const float* __restrict__ gW,
        const float* __restrict__ gb, int* __restrict__ cursor,
        int* __restrict__ entryTok, float* __restrict__ entryW,
        int* __restrict__ pos01) {
    __shared__ float hs[GTOK*HSTRIDE];
    __shared__ float gWs[DIM*NE];
    __shared__ float lg[GTOK][NE];
    __shared__ int   le01[GTOK], lli01[GTOK];
    __shared__ float lw[GTOK][2];
    __shared__ int   lcnt[NE], lbase[NE];
    int tid = threadIdx.x;
    int tok0 = blockIdx.x * GTOK;
    for (int idx = tid; idx < GTOK*30; idx += 256) {
        int row = idx / 30, c8 = idx - row*30;
        s16x8 v = *(const s16x8*)(hb + (size_t)(tok0+row)*DIM + c8*8);
#pragma unroll
        for (int i = 0; i < 8; ++i) hs[row*HSTRIDE + c8*8 + i] = bf2f(v[i]);
    }
    gate_phase(hs, gW, gb, cursor, entryTok, entryW, pos01, tok0, tid,
               gWs, lg, le01, lli01, lw, lcnt, lbase);
}

// grouped expert GEMM: 64 tokens x 240 outs; 4 waves each own 4 N-tiles; B prefetch
__global__ __launch_bounds__(256) void k_gemm(
        const short* __restrict__ hb, const short* __restrict__ wp,
        const float* __restrict__ eb, const int* __restrict__ cursor,
        const int* __restrict__ entryTok, const float* __restrict__ entryW,
        short* __restrict__ tmp, int layer) {
    int e = blockIdx.y;
    int cnt = cursor[e];
    int t0 = blockIdx.x * 64;
    if (t0 >= cnt) return;
    int ntok = min(64, cnt - t0);
    size_t base = (size_t)e*NTOK + t0;

    __shared__ short As[64*264];
    __shared__ float sw[64];
    __shared__ int stok[64];
    int tid = threadIdx.x;
    if (tid < 64) {
        if (tid < ntok) { stok[tid] = entryTok[base+tid]; sw[tid] = entryW[base+tid]; }
        else            { stok[tid] = 0;                  sw[tid] = 0.f; }
    }
    __syncthreads();
    // stage 64 rows (30 x 16B each) + zero K-pad (slots 30,31), div-free
#pragma unroll
    for (int it = 0; it < 8; ++it) {
        int idx = tid + it*256;
        int row = idx >> 5, c8 = idx & 31;
        if (c8 < 30) {
            *(s16x8*)(As + row*264 + c8*8) =
                *(const s16x8*)(hb + (size_t)stok[row]*DIM + c8*8);
        } else {
            short z[8] = {0,0,0,0,0,0,0,0};
            *(s16x8*)(As + row*264 + 240 + (c8-30)*8) = *(s16x8*)z;
        }
    }
    __syncthreads();

    int wave = tid >> 6, lane = tid & 63;
    f32x4 acc[4][4];   // [mtile][ntile]
#pragma unroll
    for (int m = 0; m < 4; ++m)
#pragma unroll
        for (int n = 0; n < 4; ++n) acc[m][n] = (f32x4){0.f,0.f,0.f,0.f};

    const short* ab = As + (lane & 15)*264 + (lane >> 4)*8;
    const short* wb = wp + (size_t)(layer*NE + e)*WPACK_PER_E + (size_t)wave*4*512 + lane*8;

    s16x8 bcur[4];
#pragma unroll
    for (int n = 0; n < 4; ++n) bcur[n] = *(const s16x8*)(wb + (size_t)n*512);

    for (int ks = 0; ks < 8; ++ks) {
        s16x8 bnxt[4];
        int ksn = (ks + 1) & 7;
#pragma unroll
        for (int n = 0; n < 4; ++n)
            bnxt[n] = *(const s16x8*)(wb + ((size_t)ksn*16 + n)*512);
        s16x8 a0 = *(const s16x8*)(ab + ks*32 + 0*16*264);
        s16x8 a1 = *(const s16x8*)(ab + ks*32 + 1*16*264);
        s16x8 a2 = *(const s16x8*)(ab + ks*32 + 2*16*264);
        s16x8 a3 = *(const s16x8*)(ab + ks*32 + 3*16*264);
#pragma unroll
        for (int n = 0; n < 4; ++n) {
            acc[0][n] = __builtin_amdgcn_mfma_f32_16x16x32_bf16(a0, bcur[n], acc[0][n], 0, 0, 0);
            acc[1][n] = __builtin_amdgcn_mfma_f32_16x16x32_bf16(a1, bcur[n], acc[1][n], 0, 0, 0);
            acc[2][n] = __builtin_amdgcn_mfma_f32_16x16x32_bf16(a2, bcur[n], acc[2][n], 0, 0, 0);
            acc[3][n] = __builtin_amdgcn_mfma_f32_16x16x32_bf16(a3, bcur[n], acc[3][n], 0, 0, 0);
        }
#pragma unroll
        for (int n = 0; n < 4; ++n) bcur[n] = bnxt[n];
    }

    const float* ebp = eb + (size_t)(layer*NE + e)*DIM;
    int mrb = (lane >> 4)*4;
#pragma unroll
    for (int n = 0; n < 4; ++n) {
        int col = (wave*4 + n)*16 + (lane & 15);
        if (col < DIM) {
            float bias = ebp[col];
#pragma unroll
            for (int m = 0; m < 4; ++m) {
#pragma unroll
                for (int r = 0; r < 4; ++r) {
                    int row = m*16 + mrb + r;
                    if (row < ntok)
                        tmp[(base + row)*DIM + col] = f2bf((acc[m][n][r] + bias) * sw[row]);
                }
            }
        }
    }
}

// fused: combine(tmp bf16)->LN->h, then gate+scatter (or pool on last layer)
// 32 tokens/block, 256 threads; each wave handles 8 tokens, 2-way ILP
__global__ __launch_bounds__(256) void k_combgate(
        const short* __restrict__ tmp, int* __restrict__ pos01,
        const float* __restrict__ gamma, const float* __restrict__ beta,
        short* __restrict__ hb, const float* __restrict__ gW,
        const float* __restrict__ gb, int* __restrict__ cursor,
        int* __restrict__ entryTok, float* __restrict__ entryW,
        const float* __restrict__ headW, float* __restrict__ out_acc, int do_gate) {
    __shared__ float hs[GTOK*HSTRIDE];
    __shared__ float gWs[DIM*NE];
    __shared__ float lg[GTOK][NE];
    __shared__ int   le01[GTOK], lli01[GTOK];
    __shared__ float lw[GTOK][2];
    __shared__ int   lcnt[NE], lbase[NE];
    int tid = threadIdx.x;
    int wave = tid >> 6, lane = tid & 63;
    int tok0 = blockIdx.x * GTOK;

    float gg[4], bb[4], hw[4];
#pragma unroll
    for (int j = 0; j < 4; ++j) {
        int d = lane + 64*j;
        gg[j] = (d < DIM) ? gamma[d] : 0.f;
        bb[j] = (d < DIM) ? beta[d]  : 0.f;
        hw[j] = (!do_gate && d < DIM) ? headW[d] : 0.f;
    }
    float pacc = 0.f;

    for (int jp = 0; jp < 4; ++jp) {
#pragma unroll
        for (int u = 0; u < 2; ++u) {
            int lt = wave*8 + jp*2 + u;
            int token = tok0 + lt;
            int p0 = pos01[2*token], p1 = pos01[2*token+1];
            const short* a = tmp + (size_t)p0*DIM;
            const short* b = tmp + (size_t)p1*DIM;
            float v[4]; float s = 0.f, q = 0.f;
#pragma unroll
            for (int j = 0; j < 4; ++j) {
                int d = lane + 64*j;
                float y = (d < DIM) ? (bf2f(a[d]) + bf2f(b[d])) : 0.f;
                v[j] = y; s += y; q += y*y;
            }
#pragma unroll
            for (int o = 32; o > 0; o >>= 1) {
                s += __shfl_xor(s, o, 64);
                q += __shfl_xor(q, o, 64);
            }
            float mean = s * (1.0f/DIM);
            float var = q * (1.0f/DIM) - mean*mean;
            float rs = rsqrtf(var + 1e-5f);
#pragma unroll
            for (int j = 0; j < 4; ++j) {
                int d = lane + 64*j;
                if (d < DIM) {
                    float hn = v[j] + (v[j] - mean) * rs * gg[j] + bb[j];
                    hs[lt*HSTRIDE + d] = hn;
                    hb[(size_t)token*DIM + d] = f2bf(hn);
                    pacc += hn * hw[j];
                }
            }
        }
    }
    __syncthreads();
    if (!do_gate) {
#pragma unroll
        for (int o = 32; o > 0; o >>= 1) pacc += __shfl_xor(pacc, o, 64);
        if (lane == 0) atomicAdd(&out_acc[tok0 / SS], pacc);
        return;
    }
    gate_phase(hs, gW, gb, cursor, entryTok, entryW, pos01, tok0, tid,
               gWs, lg, le01, lli01, lw, lcnt, lbase);
}

__global__ void k_final(const float* __restrict__ out_acc, const float* __restrict__ headb,
                        float* __restrict__ out) {
    int b = threadIdx.x;
    if (b < BB) {
        float z = out_acc[b] * (1.0f/SS) + headb[0];
        out[b] = 1.0f / (1.0f + expf(-z));
    }
}

// ---------------- launch ----------------
extern "C" void kernel_launch(void* const* d_in, const int* in_sizes, int n_in,
                              void* d_out, int out_size, void* d_ws, size_t ws_size,
                              hipStream_t stream) {
    const float* x     = (const float*)d_in[0];
    const int*   step  = (const int*)  d_in[1];
    const float* roots = (const float*)d_in[2];
    const float* projW = (const float*)d_in[3];
    const float* gateW = (const float*)d_in[4];
    const float* gateb = (const float*)d_in[5];
    const float* eW    = (const float*)d_in[6];
    const float* eb    = (const float*)d_in[7];
    const float* gamma = (const float*)d_in[8];
    const float* beta  = (const float*)d_in[9];
    const float* headW = (const float*)d_in[10];
    const float* headb = (const float*)d_in[11];
    float* out = (float*)d_out;

    char* w = (char*)d_ws;
    float* cosT    = (float*)(w + OFF_COST);
    float* sinT    = (float*)(w + OFF_SINT);
    short* hb      = (short*)(w + OFF_H);
    short* tmp     = (short*)(w + OFF_TMP);
    float* entryW  = (float*)(w + OFF_ENTW);
    float* out_acc = (float*)(w + OFF_OUTACC);
    int*   pos01   = (int*)  (w + OFF_POS01);
    int*   entryTok= (int*)  (w + OFF_ENTTOK);
    int*   cursor  = (int*)  (w + OFF_CURSOR);
    short* wpack   = (short*)(w + OFF_WPACK);

    k_tables<<<241, 256, 0, stream>>>(roots, projW, cosT, sinT, cursor, out_acc);
    k_pack<<<dim3(16, 8, 64), 64, 0, stream>>>(eW, wpack);
    k_cycle<<<NTOK, 256, 0, stream>>>(x, step, cosT, sinT, hb);
    k_gate0<<<NTOK/GTOK, 256, 0, stream>>>(hb, gateW, gateb, cursor,
                                           entryTok, entryW, pos01);

    for (int l = 0; l < DEPTH; ++l) {
        k_gemm<<<dim3(NTOK/64, NE), 256, 0, stream>>>(hb, wpack, eb, cursor + l*NE,
                                                      entryTok, entryW, tmp, l);
        int nl = (l < DEPTH-1) ? l+1 : l;
        k_combgate<<<NTOK/GTOK, 256, 0, stream>>>(tmp, pos01, gamma, beta, hb,
                                                  gateW + (size_t)nl*DIM*NE, gateb + nl*NE,
                                                  cursor + nl*NE, entryTok, entryW,
                                                  headW, out_acc, (l < DEPTH-1) ? 1 : 0);
    }

    k_final<<<1, 64, 0, stream>>>(out_acc, headb, out);
}